// Round 8
// baseline (975.709 us; speedup 1.0000x reference)
//
#include <hip/hip_runtime.h>
#include <cstddef>

typedef __attribute__((ext_vector_type(8))) short short8;
typedef __attribute__((ext_vector_type(4))) float f32x4;
typedef __attribute__((ext_vector_type(16))) float f32x16;
typedef __attribute__((address_space(3))) void lds_void;
typedef const __attribute__((address_space(1))) void glob_void;

// ---------------- workspace layout (float offsets), total 54525952 f = 208 MiB ------
static const size_t OFF_S0    = 0;         // 32
static const size_t OFF_S1    = 64;        // 256
static const size_t OFF_S2    = 320;       // 256
static const size_t OFF_S3    = 576;       // 128
static const size_t OFF_MT0   = 704;       // 768  fp32 [3][256]
static const size_t OFF_MT1   = 1472;      // 384  fp32 [3][128]
static const size_t OFF_ZERO  = 1856;      // 128 fp32 zeros page (OOB gload_lds target)
static const size_t OFF_RGBF  = 2048;      // 3*128*128 fp32 (skip-path rgb, full precision)
static const size_t OFF_IMG0  = 51200;     // 3*256*256 fp32
static const size_t OFF_RGBP  = 247808;    // 2*3*512*512 fp32 (layer3 fused to_rgb partials)
static const size_t OFF_WQ0   = 1900544;   // bf16 [1][9][256][32]  = 73728 ush (36864 f)
static const size_t OFF_WQ1   = 1937408;   // bf16 [8][9][256][32]  = 589824 ush
static const size_t OFF_WQ2   = 2232320;   // bf16 [8][9][128][32]  = 294912 ush
static const size_t OFF_WQ3   = 2379776;   // bf16 [4][9][128][32]  = 147456 ush
static const size_t OFF_FEAT  = 2453504;   // bf16 NHWC [128][128][32]
static const size_t OFF_UFEAT = 2715648;   // bf16 NHWC [256][256][32]
static const size_t OFF_X1    = 4194304;   // bf16 NHWC [256][256][256] (inside X2 region)
static const size_t OFF_X2    = 4194304;   // bf16 NHWC [512][512][128] (overwrites dead x1)
static const size_t OFF_U     = 20971520;  // bf16 NHWC [512][512][256] = 33554432 f
static const size_t OFF_X0    = 20971520;  // bf16 NHWC [256][256][256] (dead before U written)
// timeline: feat->ufeat->L0(x0@U)->L1(x0->x1)->img0(x1)->up(x1->U)->L2(U->x2)->L3(x2->rgbp)->final

__device__ __forceinline__ unsigned short f2bf(float f) {
  unsigned int u = __float_as_uint(f);
  return (unsigned short)((u + 0x7FFFu + ((u >> 16) & 1u)) >> 16);
}
__device__ __forceinline__ float b2f(short h) {
  return __uint_as_float(((unsigned int)(unsigned short)h) << 16);
}

// ---------------- prep: w_vec, styles, to_rgb modulated weights (fp32) ----------------
__global__ void __launch_bounds__(256) prep_kernel(
    const float* __restrict__ rays,
    const float* __restrict__ a0w, const float* __restrict__ a0b,
    const float* __restrict__ a1w, const float* __restrict__ a1b,
    const float* __restrict__ t0aw, const float* __restrict__ t0ab,
    const float* __restrict__ a2w, const float* __restrict__ a2b,
    const float* __restrict__ a3w, const float* __restrict__ a3b,
    const float* __restrict__ t1aw, const float* __restrict__ t1ab,
    const float* __restrict__ t0w, const float* __restrict__ t1w,
    float* __restrict__ ws)
{
  __shared__ float wv[72];
  __shared__ float st0l[256];
  __shared__ float st1l[128];
  const int tid = threadIdx.x;
  if (tid < 128) ws[OFF_ZERO + tid] = 0.f;   // zeros page for OOB gload_lds
  if (tid < 36) {
    int i = tid / 12, j = tid % 12;
    float v = rays[i * 16384] * (float)(1 << j);
    wv[tid]      = sinf(v);
    wv[36 + tid] = cosf(v);
  }
  __syncthreads();
  const float inv72 = 0.11785113019775793f;   // 1/sqrt(72)

  if (tid < 32) {
    float d = 0.f;
    for (int k = 0; k < 72; ++k) d += wv[k] * a0w[tid * 72 + k];
    ws[OFF_S0 + tid] = fmaf(d, inv72, a0b[tid]);
  }
  {
    float d = 0.f;
    for (int k = 0; k < 72; ++k) d += wv[k] * a1w[tid * 72 + k];
    ws[OFF_S1 + tid] = fmaf(d, inv72, a1b[tid]);
  }
  {
    float d = 0.f;
    for (int k = 0; k < 72; ++k) d += wv[k] * t0aw[tid * 72 + k];
    st0l[tid] = fmaf(d, inv72, t0ab[tid]) * 0.0625f;       // /sqrt(256)
  }
  {
    float d = 0.f;
    for (int k = 0; k < 72; ++k) d += wv[k] * a2w[tid * 72 + k];
    ws[OFF_S2 + tid] = fmaf(d, inv72, a2b[tid]);
  }
  if (tid < 128) {
    float d = 0.f;
    for (int k = 0; k < 72; ++k) d += wv[k] * a3w[tid * 72 + k];
    ws[OFF_S3 + tid] = fmaf(d, inv72, a3b[tid]);
  }
  if (tid < 128) {
    float d = 0.f;
    for (int k = 0; k < 72; ++k) d += wv[k] * t1aw[tid * 72 + k];
    st1l[tid] = fmaf(d, inv72, t1ab[tid]) * 0.08838834764831845f;  // /sqrt(128)
  }
  __syncthreads();
  for (int i = tid; i < 768; i += 256) ws[OFF_MT0 + i] = t0w[i] * st0l[i & 255];
  for (int i = tid; i < 384; i += 256) ws[OFF_MT1 + i] = t1w[i] * st1l[i & 127];
}

// ------------ weight modulate + demodulate -> bf16 [ci/32][tap][Co][ci%32] ------------
__global__ void __launch_bounds__(256) modw_kernel(
    const float* __restrict__ w, const float* __restrict__ s,
    unsigned short* __restrict__ wq, int Ci, int Co)
{
  const int co = blockIdx.x;
  const int n = Ci * 9;
  float local = 0.f;
  for (int i = threadIdx.x; i < n; i += 256) {
    float v = w[co * n + i] * s[i / 9];
    local += v * v;
  }
#pragma unroll
  for (int off = 32; off >= 1; off >>= 1) local += __shfl_xor(local, off);
  __shared__ float red[4];
  if ((threadIdx.x & 63) == 0) red[threadIdx.x >> 6] = local;
  __syncthreads();
  const float d = rsqrtf(red[0] + red[1] + red[2] + red[3] + 1e-8f);
  for (int i = threadIdx.x; i < n; i += 256) {
    int ci = i / 9, t = i - ci * 9;
    wq[(((size_t)(ci >> 5) * 9 + t) * Co + co) * 32 + (ci & 31)] =
        f2bf(w[co * n + i] * s[ci] * d);
  }
}

// ---------- feat: conv1x1 3->32 + relu + bn @128^2 -> NHWC bf16 + fp32 rgb planes -----
__global__ void __launch_bounds__(256) feat_kernel(
    const float* __restrict__ rgbs, const float* __restrict__ cw, const float* __restrict__ cb,
    const float* __restrict__ gam, const float* __restrict__ bet,
    const float* __restrict__ mean, const float* __restrict__ var,
    unsigned short* __restrict__ feat, float* __restrict__ rgbf)
{
  const int p = blockIdx.x * 256 + threadIdx.x;
  const float r = rgbs[p], g = rgbs[16384 + p], b = rgbs[32768 + p];
  unsigned int pk[16];
#pragma unroll
  for (int co = 0; co < 32; ++co) {
    float v = cw[co * 3] * r + cw[co * 3 + 1] * g + cw[co * 3 + 2] * b + cb[co];
    v = fmaxf(v, 0.f);
    float inv = rsqrtf(var[co] + 1e-5f);
    v = (v - mean[co]) * (inv * gam[co]) + bet[co];
    if (co < 3) rgbf[co * 16384 + p] = v;
    unsigned int h = f2bf(v);
    if ((co & 1) == 0) pk[co >> 1] = h;
    else               pk[co >> 1] |= h << 16;
  }
  uint4* dst = reinterpret_cast<uint4*>(feat + (size_t)p * 32);
#pragma unroll
  for (int q = 0; q < 4; ++q)
    dst[q] = make_uint4(pk[q * 4], pk[q * 4 + 1], pk[q * 4 + 2], pk[q * 4 + 3]);
}

// ---------------- NHWC bf16 2x antialiased upsample ----------------
__global__ void __launch_bounds__(256) up2x_nhwc_kernel(
    const unsigned short* __restrict__ in, unsigned short* __restrict__ out,
    int H, int W, int c8s /*log2(C/8)*/, int w2s /*log2(2W)*/)
{
  const int cid = blockIdx.x * 256 + threadIdx.x;
  const int k = cid & ((1 << c8s) - 1);
  const int pix = cid >> c8s;
  const int ey = pix >> w2s;
  const int ex = pix & ((1 << w2s) - 1);
  const int C = 8 << c8s;
  int ry0; float ay0, ay1;
  if (ey & 1) { ry0 = ey >> 1;       ay0 = 0.75f; ay1 = 0.25f; }
  else        { ry0 = (ey >> 1) - 1; ay0 = 0.25f; ay1 = 0.75f; }
  int cx0; float bx0, bx1;
  if (ex & 1) { cx0 = ex >> 1;       bx0 = 0.75f; bx1 = 0.25f; }
  else        { cx0 = (ex >> 1) - 1; bx0 = 0.25f; bx1 = 0.75f; }
  const short8 z = {0, 0, 0, 0, 0, 0, 0, 0};
  short8 v00 = z, v01 = z, v10 = z, v11 = z;
  const bool yo0 = (ry0 >= 0), yo1 = (ry0 + 1 < H);
  const bool xo0 = (cx0 >= 0), xo1 = (cx0 + 1 < W);
  if (yo0 && xo0) v00 = *reinterpret_cast<const short8*>(in + ((size_t)(ry0 * W + cx0) * C + k * 8));
  if (yo0 && xo1) v01 = *reinterpret_cast<const short8*>(in + ((size_t)(ry0 * W + cx0 + 1) * C + k * 8));
  if (yo1 && xo0) v10 = *reinterpret_cast<const short8*>(in + ((size_t)((ry0 + 1) * W + cx0) * C + k * 8));
  if (yo1 && xo1) v11 = *reinterpret_cast<const short8*>(in + ((size_t)((ry0 + 1) * W + cx0 + 1) * C + k * 8));
  unsigned int o[4];
#pragma unroll
  for (int j = 0; j < 8; ++j) {
    float f = ay0 * (bx0 * b2f(v00[j]) + bx1 * b2f(v01[j]))
            + ay1 * (bx0 * b2f(v10[j]) + bx1 * b2f(v11[j]));
    unsigned int h = f2bf(f);
    if ((j & 1) == 0) o[j >> 1] = h;
    else              o[j >> 1] |= h << 16;
  }
  *reinterpret_cast<uint4*>(out + (size_t)pix * C + k * 8) = make_uint4(o[0], o[1], o[2], o[3]);
}

// ---------------- conv3x3 via 32x32x16 MFMA implicit GEMM (NHWC bf16) ----------------
// Block: 8 waves (512 thr), 16x16 pixel tile, ONE 64-co group (blockIdx.y selects).
// Wave wv: 2 rows (wv*2 + (px>>4)), px = lane&31: 32 pixels; 2 co-tiles of 32.
// A (weights): row(co)=lane&31, k=(lane>>5)*8+j.  B (acts): col(px)=lane&31, same k.
// C/D: col(px)=lane&31, row(co)=(reg&3)+8*(reg>>2)+4*(lane>>5).
// Staging: global_load_lds w=16, linear LDS dest, swizzle on global source:
// slot = k ^ ((x>>1)&3) ^ ((y&1)<<1). Dbuf, stage c+1 at top of c, 1 barrier/chunk.
template <bool FUSE_RGB>
__global__ void __launch_bounds__(512) conv3x3_mfma(
    const unsigned short* __restrict__ in,   // [H][W][Ci] bf16
    const unsigned short* __restrict__ wq,   // [Ci/32][9][Co][32] bf16
    const float* __restrict__ bias,          // [Co]
    unsigned short* __restrict__ out,        // [H][W][Co] bf16 (or null)
    const float* __restrict__ rgbw,          // [3][Co] fp32 (FUSE)
    float* __restrict__ rgbp,                // [2][3][H*W] fp32 (FUSE)
    const unsigned short* __restrict__ zpage,// >=512B of zeros
    int H, int W, int Ci, int Co)
{
  const int tid  = threadIdx.x;
  const int lane = tid & 63;
  const int wv   = tid >> 6;          // 0..7 -> rows wv*2, wv*2+1
  const int px   = lane & 31;
  const int hi5  = lane >> 5;
  const int prow = px >> 4, pcol = px & 15;
  const int tpr  = W >> 4;
  const int T_y  = (blockIdx.x / tpr) << 4;
  const int T_x  = (blockIdx.x % tpr) << 4;
  const int cog  = blockIdx.y << 6;

  __shared__ short8 xs[2][1296];  // dbuf [pix 18*18][4 k-slots]
  __shared__ float  rw[FUSE_RGB ? 384 : 4];

  if (FUSE_RGB) {
    for (int i = tid; i < 3 * Co; i += 512) rw[i] = rgbw[i];
  }

  f32x16 acc0 = {0.f}, acc1 = {0.f};
#pragma unroll
  for (int i = 0; i < 16; ++i) { acc0[i] = 0.f; acc1[i] = 0.f; }

  // ---- ci-invariant per-lane staging sources (slot = j*512 + tid, linear) ----
  const unsigned short* gsrc[3];
#pragma unroll
  for (int j = 0; j < 3; ++j) {
    const int s = j * 512 + tid;
    const int pix = s >> 2, kslot = s & 3;
    const int rr = pix / 18, cc = pix - rr * 18;
    const int gy = T_y - 1 + rr, gx = T_x - 1 + cc;
    const int k = kslot ^ ((cc >> 1) & 3) ^ ((rr & 1) << 1);  // inverse swizzle on SOURCE
    const bool inb = (s < 1296) && gy >= 0 && gy < H && gx >= 0 && gx < W;
    gsrc[j] = inb ? (in + ((size_t)(gy * W + gx) * Ci + (k << 3))) : zpage;
  }

#define STAGE(c, buf)                                                              \
  {                                                                                \
    const int cb_ = (c) << 5;                                                      \
    _Pragma("unroll")                                                              \
    for (int j = 0; j < 2; ++j)                                                    \
      __builtin_amdgcn_global_load_lds((glob_void*)(gsrc[j] + cb_),                \
                                       (lds_void*)&xs[buf][j * 512 + tid], 16, 0, 0); \
    if (tid < 272)                                                                 \
      __builtin_amdgcn_global_load_lds((glob_void*)(gsrc[2] + cb_),                \
                                       (lds_void*)&xs[buf][1024 + tid], 16, 0, 0); \
  }

  // ---- A-fragment 3-slot ring over global half-chunk steps (18/chunk), dist 2 ----
  const int nch = Ci >> 5;
  const int nsteps2 = nch * 18;
  const unsigned short* wa = wq + ((size_t)(cog + px) << 5) + (hi5 << 3);
  const size_t wstride = (size_t)Co << 5;   // shorts per tap-step
  short8 apf[3][2];

#define ALOAD(SLOT, G)                                                             \
  {                                                                                \
    const unsigned short* wp_ = wa + (size_t)((G) >> 1) * wstride + (((G) & 1) << 4); \
    apf[SLOT][0] = *reinterpret_cast<const short8*>(wp_);                          \
    apf[SLOT][1] = *reinterpret_cast<const short8*>(wp_ + 1024);                   \
  }

  // prologue: stage chunk 0, prefetch A steps 0,1
  STAGE(0, 0);
  ALOAD(0, 0);
  ALOAD(1, 1);
  __syncthreads();             // drains chunk-0 staging

  for (int c = 0; c < nch; ++c) {
    const int cur = c & 1;
    if (c + 1 < nch) STAGE(c + 1, cur ^ 1);   // drain overlaps this chunk's compute

    const int base2 = c * 18;
#pragma unroll
    for (int tap = 0; tap < 9; ++tap) {
      const int ky = tap / 3, kx = tap - (tap / 3) * 3;
      const int trow = (wv << 1) + prow + ky;
      const int tcol = pcol + kx;
      const int pixb = (trow * 18 + tcol) << 2;
      const int sxor = ((tcol >> 1) & 3) ^ ((trow & 1) << 1);
#pragma unroll
      for (int ks = 0; ks < 2; ++ks) {
        const int gstep = base2 + tap * 2 + ks + 2;
        if (gstep < nsteps2) ALOAD((tap * 2 + ks + 2) % 3, gstep);
        const short8 b = xs[cur][pixb + (((ks << 1) + hi5) ^ sxor)];
        acc0 = __builtin_amdgcn_mfma_f32_32x32x16_bf16(apf[(tap * 2 + ks) % 3][0], b, acc0, 0, 0, 0);
        acc1 = __builtin_amdgcn_mfma_f32_32x32x16_bf16(apf[(tap * 2 + ks) % 3][1], b, acc1, 0, 0, 0);
      }
    }
    __syncthreads();           // readers of buf[cur] done; staging c+1 drained
  }
#undef STAGE
#undef ALOAD

  // ---- epilogue ----
  const float rt2 = 1.41421356237309515f;
  const int gy = T_y + (wv << 1) + prow;
  const int gx = T_x + pcol;
  if (!FUSE_RGB) {
#pragma unroll
    for (int ct = 0; ct < 2; ++ct) {
#pragma unroll
      for (int q = 0; q < 4; ++q) {
        const int cb = cog + (ct << 5) + (q << 3) + (hi5 << 2);
        const f32x4 bi = *reinterpret_cast<const f32x4*>(bias + cb);
        unsigned short h[4];
#pragma unroll
        for (int i = 0; i < 4; ++i) {
          float vv = (ct == 0 ? acc0[q * 4 + i] : acc1[q * 4 + i]) + bi[i];
          vv = (vv >= 0.f) ? vv : 0.2f * vv;
          vv *= rt2;
          vv = fminf(fmaxf(vv, -256.f), 256.f);
          h[i] = f2bf(vv);
        }
        uint2 pk;
        pk.x = (unsigned int)h[0] | ((unsigned int)h[1] << 16);
        pk.y = (unsigned int)h[2] | ((unsigned int)h[3] << 16);
        *reinterpret_cast<uint2*>(out + (size_t)(gy * W + gx) * Co + cb) = pk;
      }
    }
  } else {
    float p0 = 0.f, p1 = 0.f, p2 = 0.f;
#pragma unroll
    for (int ct = 0; ct < 2; ++ct) {
#pragma unroll
      for (int q = 0; q < 4; ++q) {
        const int cb = cog + (ct << 5) + (q << 3) + (hi5 << 2);
        const f32x4 bi = *reinterpret_cast<const f32x4*>(bias + cb);
#pragma unroll
        for (int i = 0; i < 4; ++i) {
          float vv = (ct == 0 ? acc0[q * 4 + i] : acc1[q * 4 + i]) + bi[i];
          vv = (vv >= 0.f) ? vv : 0.2f * vv;
          vv *= rt2;
          vv = fminf(fmaxf(vv, -256.f), 256.f);
          p0 = fmaf(rw[cb + i], vv, p0);
          p1 = fmaf(rw[Co + cb + i], vv, p1);
          p2 = fmaf(rw[2 * Co + cb + i], vv, p2);
        }
      }
    }
    p0 += __shfl_xor(p0, 32);
    p1 += __shfl_xor(p1, 32);
    p2 += __shfl_xor(p2, 32);
    if (hi5 == 0) {
      const size_t HWs = (size_t)H * W;
      const size_t pxi = (size_t)gy * W + gx;
      rgbp[((size_t)blockIdx.y * 3 + 0) * HWs + pxi] = p0;
      rgbp[((size_t)blockIdx.y * 3 + 1) * HWs + pxi] = p1;
      rgbp[((size_t)blockIdx.y * 3 + 2) * HWs + pxi] = p2;
    }
  }
}

// ---------------- fp32-plane upfirdn2d sampler ----------------
__device__ __forceinline__ float up2x_sample(const float* __restrict__ im, int H, int W,
                                             int oy, int ox)
{
  int my = oy >> 1, mx = ox >> 1;
  int ry0; float ay0, ay1;
  if (oy & 1) { ry0 = my;     ay0 = 0.75f; ay1 = 0.25f; }
  else        { ry0 = my - 1; ay0 = 0.25f; ay1 = 0.75f; }
  int cx0; float bx0, bx1;
  if (ox & 1) { cx0 = mx;     bx0 = 0.75f; bx1 = 0.25f; }
  else        { cx0 = mx - 1; bx0 = 0.25f; bx1 = 0.75f; }
  float v00 = (ry0 >= 0    && cx0 >= 0   ) ? im[ry0 * W + cx0]           : 0.f;
  float v01 = (ry0 >= 0    && cx0 + 1 < W) ? im[ry0 * W + cx0 + 1]       : 0.f;
  float v10 = (ry0 + 1 < H && cx0 >= 0   ) ? im[(ry0 + 1) * W + cx0]     : 0.f;
  float v11 = (ry0 + 1 < H && cx0 + 1 < W) ? im[(ry0 + 1) * W + cx0 + 1] : 0.f;
  return ay0 * (bx0 * v00 + bx1 * v01) + ay1 * (bx0 * v10 + bx1 * v11);
}

// ---------------- img0 = up2x(rgb_fp32) + clip(to_rgb0(x1)) @256^2 ----------------
__global__ void __launch_bounds__(256) img0_kernel(
    const float* __restrict__ rgbf, const unsigned short* __restrict__ x1,
    const float* __restrict__ mt0g, const float* __restrict__ tb,
    float* __restrict__ img0)
{
  __shared__ float mt[768];
  const int tid = threadIdx.x;
  for (int i = tid; i < 768; i += 256) mt[i] = mt0g[i];
  __syncthreads();
  const int p = blockIdx.x * 256 + tid;
  const unsigned short* xp = x1 + (size_t)p * 256;
  float a0 = 0.f, a1 = 0.f, a2 = 0.f;
  for (int i8 = 0; i8 < 32; ++i8) {
    const short8 v = *reinterpret_cast<const short8*>(xp + i8 * 8);
#pragma unroll
    for (int j = 0; j < 8; ++j) {
      const float xv = b2f(v[j]);
      const int ci = i8 * 8 + j;
      a0 = fmaf(mt[ci],       xv, a0);
      a1 = fmaf(mt[256 + ci], xv, a1);
      a2 = fmaf(mt[512 + ci], xv, a2);
    }
  }
  const int oy = p >> 8, ox = p & 255;
  float av[3] = {a0, a1, a2};
#pragma unroll
  for (int o = 0; o < 3; ++o) {
    float y = fminf(fmaxf(av[o] + tb[o], -256.f), 256.f);
    img0[o * 65536 + p] = up2x_sample(rgbf + o * 16384, 128, 128, oy, ox) + y;
  }
}

// ---------------- out = up2x(img0) + clip(sum rgbp + tb) @512^2 ----------------
__global__ void __launch_bounds__(256) final_kernel(
    const float* __restrict__ img0, const float* __restrict__ rgbp,
    const float* __restrict__ tb, float* __restrict__ out)
{
  const int p = blockIdx.x * 256 + threadIdx.x;
  const int oy = p >> 9, ox = p & 511;
#pragma unroll
  for (int o = 0; o < 3; ++o) {
    float a = rgbp[(0 * 3 + o) * 262144 + p] + rgbp[(1 * 3 + o) * 262144 + p];
    float y = fminf(fmaxf(a + tb[o], -256.f), 256.f);
    out[o * 262144 + p] = up2x_sample(img0 + o * 65536, 256, 256, oy, ox) + y;
  }
}

// ---------------- launch ----------------
extern "C" void kernel_launch(void* const* d_in, const int* in_sizes, int n_in,
                              void* d_out, int out_size, void* d_ws, size_t ws_size,
                              hipStream_t stream)
{
  const float* rays   = (const float*)d_in[0];
  const float* rgbs   = (const float*)d_in[1];
  const float* conv_w = (const float*)d_in[2];
  const float* conv_b = (const float*)d_in[3];
  const float* bn_g   = (const float*)d_in[4];
  const float* bn_b   = (const float*)d_in[5];
  const float* bn_m   = (const float*)d_in[6];
  const float* bn_v   = (const float*)d_in[7];
  const float* a0_w   = (const float*)d_in[8];
  const float* a0_b   = (const float*)d_in[9];
  const float* w0     = (const float*)d_in[10];
  const float* b0     = (const float*)d_in[11];
  const float* a1_w   = (const float*)d_in[12];
  const float* a1_b   = (const float*)d_in[13];
  const float* w1     = (const float*)d_in[14];
  const float* b1     = (const float*)d_in[15];
  const float* t0_aw  = (const float*)d_in[16];
  const float* t0_ab  = (const float*)d_in[17];
  const float* t0_w   = (const float*)d_in[18];
  const float* t0_b   = (const float*)d_in[19];
  const float* a2_w   = (const float*)d_in[20];
  const float* a2_b   = (const float*)d_in[21];
  const float* w2     = (const float*)d_in[22];
  const float* b2     = (const float*)d_in[23];
  const float* a3_w   = (const float*)d_in[24];
  const float* a3_b   = (const float*)d_in[25];
  const float* w3     = (const float*)d_in[26];
  const float* b3     = (const float*)d_in[27];
  const float* t1_aw  = (const float*)d_in[28];
  const float* t1_ab  = (const float*)d_in[29];
  const float* t1_w   = (const float*)d_in[30];
  const float* t1_b   = (const float*)d_in[31];

  float* ws  = (float*)d_ws;
  float* out = (float*)d_out;

  unsigned short* wq0   = (unsigned short*)(ws + OFF_WQ0);
  unsigned short* wq1   = (unsigned short*)(ws + OFF_WQ1);
  unsigned short* wq2   = (unsigned short*)(ws + OFF_WQ2);
  unsigned short* wq3   = (unsigned short*)(ws + OFF_WQ3);
  unsigned short* featb = (unsigned short*)(ws + OFF_FEAT);
  unsigned short* ufeat = (unsigned short*)(ws + OFF_UFEAT);
  unsigned short* x0b   = (unsigned short*)(ws + OFF_X0);
  unsigned short* x1b   = (unsigned short*)(ws + OFF_X1);
  unsigned short* x2b   = (unsigned short*)(ws + OFF_X2);
  unsigned short* Ub    = (unsigned short*)(ws + OFF_U);
  const unsigned short* zpage = (const unsigned short*)(ws + OFF_ZERO);

  prep_kernel<<<1, 256, 0, stream>>>(rays, a0_w, a0_b, a1_w, a1_b, t0_aw, t0_ab,
                                     a2_w, a2_b, a3_w, a3_b, t1_aw, t1_ab,
                                     t0_w, t1_w, ws);
  modw_kernel<<<256, 256, 0, stream>>>(w0, ws + OFF_S0, wq0, 32, 256);
  modw_kernel<<<256, 256, 0, stream>>>(w1, ws + OFF_S1, wq1, 256, 256);
  modw_kernel<<<128, 256, 0, stream>>>(w2, ws + OFF_S2, wq2, 256, 128);
  modw_kernel<<<128, 256, 0, stream>>>(w3, ws + OFF_S3, wq3, 128, 128);
  feat_kernel<<<64, 256, 0, stream>>>(rgbs, conv_w, conv_b, bn_g, bn_b, bn_m, bn_v,
                                      featb, ws + OFF_RGBF);
  // up(feat) -> ufeat  (128->256, C=32: c8s=2, w2s=8)
  up2x_nhwc_kernel<<<1024, 256, 0, stream>>>(featb, ufeat, 128, 128, 2, 8);
  // L0: ufeat(32) -> x0(256) @256^2   (4 co-groups of 64)
  conv3x3_mfma<false><<<dim3(256, 4), 512, 0, stream>>>(
      ufeat, wq0, b0, x0b, nullptr, nullptr, zpage, 256, 256, 32, 256);
  // L1: x0(256) -> x1(256) @256^2
  conv3x3_mfma<false><<<dim3(256, 4), 512, 0, stream>>>(
      x0b, wq1, b1, x1b, nullptr, nullptr, zpage, 256, 256, 256, 256);
  // img0 = up2x(rgb) + to_rgb0(x1)
  img0_kernel<<<256, 256, 0, stream>>>(ws + OFF_RGBF, x1b, ws + OFF_MT0, t0_b,
                                       ws + OFF_IMG0);
  // up(x1) -> U  (256->512, C=256: c8s=5, w2s=9)
  up2x_nhwc_kernel<<<32768, 256, 0, stream>>>(x1b, Ub, 256, 256, 5, 9);
  // L2: U(256) -> x2(128) @512^2  (2 co-groups of 64)
  conv3x3_mfma<false><<<dim3(1024, 2), 512, 0, stream>>>(
      Ub, wq2, b2, x2b, nullptr, nullptr, zpage, 512, 512, 256, 128);
  // L3: x2(128) -> fused to_rgb1 partials @512^2 (blockIdx.y = partial group)
  conv3x3_mfma<true><<<dim3(1024, 2), 512, 0, stream>>>(
      x2b, wq3, b3, nullptr, ws + OFF_MT1, ws + OFF_RGBP, zpage, 512, 512, 128, 128);
  // out = up2x(img0) + clip(rgbp sum + t1_b)
  final_kernel<<<1024, 256, 0, stream>>>(ws + OFF_IMG0, ws + OFF_RGBP, t1_b, out);
}

// Round 9
// 467.538 us; speedup vs baseline: 2.0869x; 2.0869x over previous
//
#include <hip/hip_runtime.h>
#include <cstddef>

typedef __attribute__((ext_vector_type(8))) short short8;
typedef __attribute__((ext_vector_type(4))) float f32x4;
typedef __attribute__((address_space(3))) void lds_void;
typedef const __attribute__((address_space(1))) void glob_void;

// ---------------- workspace layout (float offsets), total 54525952 f = 208 MiB ------
static const size_t OFF_S0    = 0;         // 32
static const size_t OFF_S1    = 64;        // 256
static const size_t OFF_S2    = 320;       // 256
static const size_t OFF_S3    = 576;       // 128
static const size_t OFF_MT0   = 704;       // 768  fp32 [3][256]
static const size_t OFF_MT1   = 1472;      // 384  fp32 [3][128]
static const size_t OFF_ZERO  = 1856;      // 128 fp32 zeros page (OOB gload_lds target)
static const size_t OFF_RGBF  = 2048;      // 3*128*128 fp32 (skip-path rgb, full precision)
static const size_t OFF_IMG0  = 51200;     // 3*256*256 fp32
static const size_t OFF_RGBP  = 247808;    // 2*3*512*512 fp32 (layer3 fused to_rgb partials)
static const size_t OFF_WQ0   = 1900544;   // bf16 [1][9][256][32]  = 73728 ush (36864 f)
static const size_t OFF_WQ1   = 1937408;   // bf16 [8][9][256][32]  = 589824 ush
static const size_t OFF_WQ2   = 2232320;   // bf16 [8][9][128][32]  = 294912 ush
static const size_t OFF_WQ3   = 2379776;   // bf16 [4][9][128][32]  = 147456 ush
static const size_t OFF_FEAT  = 2453504;   // bf16 NHWC [128][128][32]
static const size_t OFF_UFEAT = 2715648;   // bf16 NHWC [256][256][32]
static const size_t OFF_X1    = 4194304;   // bf16 NHWC [256][256][256] (inside X2 region)
static const size_t OFF_X2    = 4194304;   // bf16 NHWC [512][512][128] (overwrites dead x1)
static const size_t OFF_U     = 20971520;  // bf16 NHWC [512][512][256] = 33554432 f
static const size_t OFF_X0    = 20971520;  // bf16 NHWC [256][256][256] (dead before U written)
// timeline: feat->ufeat->L0(x0@U)->L1(x0->x1)->img0(x1)->up(x1->U)->L2(U->x2)->L3(x2->rgbp)->final

__device__ __forceinline__ unsigned short f2bf(float f) {
  unsigned int u = __float_as_uint(f);
  return (unsigned short)((u + 0x7FFFu + ((u >> 16) & 1u)) >> 16);
}
__device__ __forceinline__ float b2f(short h) {
  return __uint_as_float(((unsigned int)(unsigned short)h) << 16);
}

// ---------------- prep: w_vec, styles, to_rgb modulated weights (fp32) ----------------
__global__ void __launch_bounds__(256) prep_kernel(
    const float* __restrict__ rays,
    const float* __restrict__ a0w, const float* __restrict__ a0b,
    const float* __restrict__ a1w, const float* __restrict__ a1b,
    const float* __restrict__ t0aw, const float* __restrict__ t0ab,
    const float* __restrict__ a2w, const float* __restrict__ a2b,
    const float* __restrict__ a3w, const float* __restrict__ a3b,
    const float* __restrict__ t1aw, const float* __restrict__ t1ab,
    const float* __restrict__ t0w, const float* __restrict__ t1w,
    float* __restrict__ ws)
{
  __shared__ float wv[72];
  __shared__ float st0l[256];
  __shared__ float st1l[128];
  const int tid = threadIdx.x;
  if (tid < 128) ws[OFF_ZERO + tid] = 0.f;   // zeros page for OOB gload_lds
  if (tid < 36) {
    int i = tid / 12, j = tid % 12;
    float v = rays[i * 16384] * (float)(1 << j);
    wv[tid]      = sinf(v);
    wv[36 + tid] = cosf(v);
  }
  __syncthreads();
  const float inv72 = 0.11785113019775793f;   // 1/sqrt(72)

  if (tid < 32) {
    float d = 0.f;
    for (int k = 0; k < 72; ++k) d += wv[k] * a0w[tid * 72 + k];
    ws[OFF_S0 + tid] = fmaf(d, inv72, a0b[tid]);
  }
  {
    float d = 0.f;
    for (int k = 0; k < 72; ++k) d += wv[k] * a1w[tid * 72 + k];
    ws[OFF_S1 + tid] = fmaf(d, inv72, a1b[tid]);
  }
  {
    float d = 0.f;
    for (int k = 0; k < 72; ++k) d += wv[k] * t0aw[tid * 72 + k];
    st0l[tid] = fmaf(d, inv72, t0ab[tid]) * 0.0625f;       // /sqrt(256)
  }
  {
    float d = 0.f;
    for (int k = 0; k < 72; ++k) d += wv[k] * a2w[tid * 72 + k];
    ws[OFF_S2 + tid] = fmaf(d, inv72, a2b[tid]);
  }
  if (tid < 128) {
    float d = 0.f;
    for (int k = 0; k < 72; ++k) d += wv[k] * a3w[tid * 72 + k];
    ws[OFF_S3 + tid] = fmaf(d, inv72, a3b[tid]);
  }
  if (tid < 128) {
    float d = 0.f;
    for (int k = 0; k < 72; ++k) d += wv[k] * t1aw[tid * 72 + k];
    st1l[tid] = fmaf(d, inv72, t1ab[tid]) * 0.08838834764831845f;  // /sqrt(128)
  }
  __syncthreads();
  for (int i = tid; i < 768; i += 256) ws[OFF_MT0 + i] = t0w[i] * st0l[i & 255];
  for (int i = tid; i < 384; i += 256) ws[OFF_MT1 + i] = t1w[i] * st1l[i & 127];
}

// ------------ weight modulate + demodulate -> bf16 [ci/32][tap][Co][ci%32] ------------
__global__ void __launch_bounds__(256) modw_kernel(
    const float* __restrict__ w, const float* __restrict__ s,
    unsigned short* __restrict__ wq, int Ci, int Co)
{
  const int co = blockIdx.x;
  const int n = Ci * 9;
  float local = 0.f;
  for (int i = threadIdx.x; i < n; i += 256) {
    float v = w[co * n + i] * s[i / 9];
    local += v * v;
  }
#pragma unroll
  for (int off = 32; off >= 1; off >>= 1) local += __shfl_xor(local, off);
  __shared__ float red[4];
  if ((threadIdx.x & 63) == 0) red[threadIdx.x >> 6] = local;
  __syncthreads();
  const float d = rsqrtf(red[0] + red[1] + red[2] + red[3] + 1e-8f);
  for (int i = threadIdx.x; i < n; i += 256) {
    int ci = i / 9, t = i - ci * 9;
    wq[(((size_t)(ci >> 5) * 9 + t) * Co + co) * 32 + (ci & 31)] =
        f2bf(w[co * n + i] * s[ci] * d);
  }
}

// ---------- feat: conv1x1 3->32 + relu + bn @128^2 -> NHWC bf16 + fp32 rgb planes -----
__global__ void __launch_bounds__(256) feat_kernel(
    const float* __restrict__ rgbs, const float* __restrict__ cw, const float* __restrict__ cb,
    const float* __restrict__ gam, const float* __restrict__ bet,
    const float* __restrict__ mean, const float* __restrict__ var,
    unsigned short* __restrict__ feat, float* __restrict__ rgbf)
{
  const int p = blockIdx.x * 256 + threadIdx.x;
  const float r = rgbs[p], g = rgbs[16384 + p], b = rgbs[32768 + p];
  unsigned int pk[16];
#pragma unroll
  for (int co = 0; co < 32; ++co) {
    float v = cw[co * 3] * r + cw[co * 3 + 1] * g + cw[co * 3 + 2] * b + cb[co];
    v = fmaxf(v, 0.f);
    float inv = rsqrtf(var[co] + 1e-5f);
    v = (v - mean[co]) * (inv * gam[co]) + bet[co];
    if (co < 3) rgbf[co * 16384 + p] = v;
    unsigned int h = f2bf(v);
    if ((co & 1) == 0) pk[co >> 1] = h;
    else               pk[co >> 1] |= h << 16;
  }
  uint4* dst = reinterpret_cast<uint4*>(feat + (size_t)p * 32);
#pragma unroll
  for (int q = 0; q < 4; ++q)
    dst[q] = make_uint4(pk[q * 4], pk[q * 4 + 1], pk[q * 4 + 2], pk[q * 4 + 3]);
}

// ---------------- NHWC bf16 2x antialiased upsample ----------------
__global__ void __launch_bounds__(256) up2x_nhwc_kernel(
    const unsigned short* __restrict__ in, unsigned short* __restrict__ out,
    int H, int W, int c8s /*log2(C/8)*/, int w2s /*log2(2W)*/)
{
  const int cid = blockIdx.x * 256 + threadIdx.x;
  const int k = cid & ((1 << c8s) - 1);
  const int pix = cid >> c8s;
  const int ey = pix >> w2s;
  const int ex = pix & ((1 << w2s) - 1);
  const int C = 8 << c8s;
  int ry0; float ay0, ay1;
  if (ey & 1) { ry0 = ey >> 1;       ay0 = 0.75f; ay1 = 0.25f; }
  else        { ry0 = (ey >> 1) - 1; ay0 = 0.25f; ay1 = 0.75f; }
  int cx0; float bx0, bx1;
  if (ex & 1) { cx0 = ex >> 1;       bx0 = 0.75f; bx1 = 0.25f; }
  else        { cx0 = (ex >> 1) - 1; bx0 = 0.25f; bx1 = 0.75f; }
  const short8 z = {0, 0, 0, 0, 0, 0, 0, 0};
  short8 v00 = z, v01 = z, v10 = z, v11 = z;
  const bool yo0 = (ry0 >= 0), yo1 = (ry0 + 1 < H);
  const bool xo0 = (cx0 >= 0), xo1 = (cx0 + 1 < W);
  if (yo0 && xo0) v00 = *reinterpret_cast<const short8*>(in + ((size_t)(ry0 * W + cx0) * C + k * 8));
  if (yo0 && xo1) v01 = *reinterpret_cast<const short8*>(in + ((size_t)(ry0 * W + cx0 + 1) * C + k * 8));
  if (yo1 && xo0) v10 = *reinterpret_cast<const short8*>(in + ((size_t)((ry0 + 1) * W + cx0) * C + k * 8));
  if (yo1 && xo1) v11 = *reinterpret_cast<const short8*>(in + ((size_t)((ry0 + 1) * W + cx0 + 1) * C + k * 8));
  unsigned int o[4];
#pragma unroll
  for (int j = 0; j < 8; ++j) {
    float f = ay0 * (bx0 * b2f(v00[j]) + bx1 * b2f(v01[j]))
            + ay1 * (bx0 * b2f(v10[j]) + bx1 * b2f(v11[j]));
    unsigned int h = f2bf(f);
    if ((j & 1) == 0) o[j >> 1] = h;
    else              o[j >> 1] |= h << 16;
  }
  *reinterpret_cast<uint4*>(out + (size_t)pix * C + k * 8) = make_uint4(o[0], o[1], o[2], o[3]);
}

// ---------------- conv3x3 via MFMA implicit GEMM (NHWC bf16) ----------------
// Block: 8 waves (512 thr), 16x16 pixel tile, TWO 64-co groups sharing the staged tile.
// Waves 0-3 -> co-group 0 (rows (wv&3)*4), waves 4-7 -> co-group 1.
// acc[cf][r]: co = cog + cf*16 + (lane>>4)*4 + reg ; pixel col = lane&15.
// Inner loop is kx-MAJOR with a rolling 4-register B window over the 6 rows each
// (kx, wave) needs -> 18 ds_read_b128/chunk instead of 36 (LDS-BW was the binding
// constraint: 36 reads x 12cyc = 3.0 cyc/MFMA vs 1.21 MFMA pipe).
// Staging: global_load_lds w=16, linear LDS dest, k-swizzle on global source; dbuf,
// stage c+1 at top of chunk c, 1 barrier/chunk. A: per-chunk 2-slot dist-1 ring.
template <bool FUSE_RGB>
__global__ void __launch_bounds__(512) conv3x3_mfma(
    const unsigned short* __restrict__ in,   // [H][W][Ci] bf16
    const unsigned short* __restrict__ wq,   // [Ci/32][9][Co][32] bf16
    const float* __restrict__ bias,          // [Co]
    unsigned short* __restrict__ out,        // [H][W][Co] bf16 (or null)
    const float* __restrict__ rgbw,          // [3][Co] fp32 (FUSE)
    float* __restrict__ rgbp,                // [2][3][H*W] fp32 (FUSE)
    const unsigned short* __restrict__ zpage,// >=512B of zeros
    int H, int W, int Ci, int Co)
{
  const int tid  = threadIdx.x;
  const int lane = tid & 63;
  const int wv   = tid >> 6;          // 0..7
  const int wr   = wv & 3;            // row group within tile
  const int wg   = wv >> 2;           // co-group within block (0/1)
  const int lo   = lane & 15, hi = lane >> 4;
  const int tpr  = W >> 4;
  const int T_y  = (blockIdx.x / tpr) << 4;
  const int T_x  = (blockIdx.x % tpr) << 4;
  const int cog  = (blockIdx.y * 2 + wg) << 6;

  __shared__ short8 xs[2][1296];  // dbuf [pix 18*18][4 k-slots]; slot s' = k^((x>>1)&3)
  __shared__ float  rw[FUSE_RGB ? 384 : 4];

  if (FUSE_RGB) {
    for (int i = tid; i < 3 * Co; i += 512) rw[i] = rgbw[i];
  }

  f32x4 acc[4][4];
#pragma unroll
  for (int a = 0; a < 4; ++a)
#pragma unroll
    for (int b = 0; b < 4; ++b) acc[a][b] = (f32x4){0.f, 0.f, 0.f, 0.f};

  // ---- ci-invariant per-lane staging sources (slot = j*512 + tid, linear) ----
  const unsigned short* gsrc[3];
#pragma unroll
  for (int j = 0; j < 3; ++j) {
    const int s = j * 512 + tid;
    const int pix = s >> 2, kslot = s & 3;
    const int rr = pix / 18, cc = pix - rr * 18;
    const int gy = T_y - 1 + rr, gx = T_x - 1 + cc;
    const int k = kslot ^ ((cc >> 1) & 3);      // inverse swizzle on the SOURCE
    const bool inb = (s < 1296) && gy >= 0 && gy < H && gx >= 0 && gx < W;
    gsrc[j] = inb ? (in + ((size_t)(gy * W + gx) * Ci + (k << 3))) : zpage;
  }

#define STAGE(c, buf)                                                              \
  {                                                                                \
    const int cb_ = (c) << 5;                                                      \
    _Pragma("unroll")                                                              \
    for (int j = 0; j < 2; ++j)                                                    \
      __builtin_amdgcn_global_load_lds((glob_void*)(gsrc[j] + cb_),                \
                                       (lds_void*)&xs[buf][j * 512 + tid], 16, 0, 0); \
    if (tid < 272)                                                                 \
      __builtin_amdgcn_global_load_lds((glob_void*)(gsrc[2] + cb_),                \
                                       (lds_void*)&xs[buf][1024 + tid], 16, 0, 0); \
  }

  // ---- A fragments: per-chunk 2-slot ring, kx-major tap order, dist-1 prefetch ----
  const int nch = Ci >> 5;
  const unsigned short* wa = wq + ((size_t)(cog + lo) << 5) + (hi << 3);
  const int wstride = Co << 5;   // shorts per tap step
  short8 apf[2][4];

#define ALOAD(SLOT, STEP)                                                          \
  {                                                                                \
    const unsigned short* wp_ = wa + (size_t)(STEP) * wstride;                     \
    _Pragma("unroll")                                                              \
    for (int cf = 0; cf < 4; ++cf)                                                 \
      apf[SLOT][cf] = *reinterpret_cast<const short8*>(wp_ + (cf << 9));           \
  }

  // prologue: stage chunk 0
  STAGE(0, 0);
  __syncthreads();             // drains chunk-0 staging

  const int rstride = 18 << 2;                       // LDS elems per tile row
  for (int c = 0; c < nch; ++c) {
    const int cur = c & 1;
    if (c + 1 < nch) STAGE(c + 1, cur ^ 1);   // drain overlaps this chunk's compute
    const int base = c * 9;
    ALOAD(0, base);                            // tap 0 (kx=0, ky=0)

#pragma unroll
    for (int kx = 0; kx < 3; ++kx) {
      const int tx2  = lo + kx;
      const int xv_  = hi ^ ((tx2 >> 1) & 3);
      const int rowb = (((wr << 2) * 18 + tx2) << 2) + xv_;
      // rolling 4-register window over rows wr*4 .. wr*4+5
      short8 b0 = xs[cur][rowb];
      short8 b1 = xs[cur][rowb + rstride];
      short8 b2 = xs[cur][rowb + 2 * rstride];
      short8 b3 = xs[cur][rowb + 3 * rstride];

      // position j = kx*3 + ky; tap(j) = (j%3)*3 + j/3; slot = j&1
      // ---- ky = 0: rows r+0 -> b0..b3, A slot (kx*3)&1 ----
      {
        constexpr int J0[3] = {0, 3, 6};
        const int j = J0[0] + 0; (void)j;
      }
      if (kx * 3 + 1 <= 8) ALOAD((kx * 3 + 1) & 1, base + ((kx * 3 + 1) % 3) * 3 + (kx * 3 + 1) / 3);
#pragma unroll
      for (int cf = 0; cf < 4; ++cf) {
        acc[cf][0] = __builtin_amdgcn_mfma_f32_16x16x32_bf16(apf[(kx * 3) & 1][cf], b0, acc[cf][0], 0, 0, 0);
        acc[cf][1] = __builtin_amdgcn_mfma_f32_16x16x32_bf16(apf[(kx * 3) & 1][cf], b1, acc[cf][1], 0, 0, 0);
        acc[cf][2] = __builtin_amdgcn_mfma_f32_16x16x32_bf16(apf[(kx * 3) & 1][cf], b2, acc[cf][2], 0, 0, 0);
        acc[cf][3] = __builtin_amdgcn_mfma_f32_16x16x32_bf16(apf[(kx * 3) & 1][cf], b3, acc[cf][3], 0, 0, 0);
      }
      // ---- ky = 1: rows r+1 -> b1,b2,b3,(new)b0 ----
      b0 = xs[cur][rowb + 4 * rstride];
      if (kx * 3 + 2 <= 8) ALOAD((kx * 3 + 2) & 1, base + ((kx * 3 + 2) % 3) * 3 + (kx * 3 + 2) / 3);
#pragma unroll
      for (int cf = 0; cf < 4; ++cf) {
        acc[cf][0] = __builtin_amdgcn_mfma_f32_16x16x32_bf16(apf[(kx * 3 + 1) & 1][cf], b1, acc[cf][0], 0, 0, 0);
        acc[cf][1] = __builtin_amdgcn_mfma_f32_16x16x32_bf16(apf[(kx * 3 + 1) & 1][cf], b2, acc[cf][1], 0, 0, 0);
        acc[cf][2] = __builtin_amdgcn_mfma_f32_16x16x32_bf16(apf[(kx * 3 + 1) & 1][cf], b3, acc[cf][2], 0, 0, 0);
        acc[cf][3] = __builtin_amdgcn_mfma_f32_16x16x32_bf16(apf[(kx * 3 + 1) & 1][cf], b0, acc[cf][3], 0, 0, 0);
      }
      // ---- ky = 2: rows r+2 -> b2,b3,b0,(new)b1 ----
      b1 = xs[cur][rowb + 5 * rstride];
      if (kx * 3 + 3 <= 8) ALOAD((kx * 3 + 3) & 1, base + ((kx * 3 + 3) % 3) * 3 + (kx * 3 + 3) / 3);
#pragma unroll
      for (int cf = 0; cf < 4; ++cf) {
        acc[cf][0] = __builtin_amdgcn_mfma_f32_16x16x32_bf16(apf[(kx * 3 + 2) & 1][cf], b2, acc[cf][0], 0, 0, 0);
        acc[cf][1] = __builtin_amdgcn_mfma_f32_16x16x32_bf16(apf[(kx * 3 + 2) & 1][cf], b3, acc[cf][1], 0, 0, 0);
        acc[cf][2] = __builtin_amdgcn_mfma_f32_16x16x32_bf16(apf[(kx * 3 + 2) & 1][cf], b0, acc[cf][2], 0, 0, 0);
        acc[cf][3] = __builtin_amdgcn_mfma_f32_16x16x32_bf16(apf[(kx * 3 + 2) & 1][cf], b1, acc[cf][3], 0, 0, 0);
      }
    }
    __syncthreads();           // readers of buf[cur] done; staging c+1 drained
  }
#undef STAGE
#undef ALOAD

  // ---- epilogue ----
  const float rt2 = 1.41421356237309515f;
#pragma unroll
  for (int r = 0; r < 4; ++r) {
    const int gy = T_y + (wr << 2) + r;
    const int gx = T_x + lo;
    if (!FUSE_RGB) {
#pragma unroll
      for (int cf = 0; cf < 4; ++cf) {
        const int cb = cog + (cf << 4) + (hi << 2);
        const f32x4 bi = *reinterpret_cast<const f32x4*>(bias + cb);
        unsigned short h[4];
#pragma unroll
        for (int reg = 0; reg < 4; ++reg) {
          float vv = acc[cf][r][reg] + bi[reg];
          vv = (vv >= 0.f) ? vv : 0.2f * vv;
          vv *= rt2;
          vv = fminf(fmaxf(vv, -256.f), 256.f);
          h[reg] = f2bf(vv);
        }
        uint2 pk;
        pk.x = (unsigned int)h[0] | ((unsigned int)h[1] << 16);
        pk.y = (unsigned int)h[2] | ((unsigned int)h[3] << 16);
        *reinterpret_cast<uint2*>(out + (size_t)(gy * W + gx) * Co + cb) = pk;
      }
    } else {
      float p0 = 0.f, p1 = 0.f, p2 = 0.f;
#pragma unroll
      for (int cf = 0; cf < 4; ++cf) {
        const int cb = cog + (cf << 4) + (hi << 2);
        const f32x4 bi = *reinterpret_cast<const f32x4*>(bias + cb);
#pragma unroll
        for (int reg = 0; reg < 4; ++reg) {
          float vv = acc[cf][r][reg] + bi[reg];
          vv = (vv >= 0.f) ? vv : 0.2f * vv;
          vv *= rt2;
          vv = fminf(fmaxf(vv, -256.f), 256.f);
          p0 = fmaf(rw[cb + reg], vv, p0);
          p1 = fmaf(rw[Co + cb + reg], vv, p1);
          p2 = fmaf(rw[2 * Co + cb + reg], vv, p2);
        }
      }
      p0 += __shfl_xor(p0, 16); p0 += __shfl_xor(p0, 32);
      p1 += __shfl_xor(p1, 16); p1 += __shfl_xor(p1, 32);
      p2 += __shfl_xor(p2, 16); p2 += __shfl_xor(p2, 32);
      if (hi == 0) {
        const size_t HWs = (size_t)H * W;
        const size_t px  = (size_t)gy * W + gx;
        rgbp[((size_t)wg * 3 + 0) * HWs + px] = p0;
        rgbp[((size_t)wg * 3 + 1) * HWs + px] = p1;
        rgbp[((size_t)wg * 3 + 2) * HWs + px] = p2;
      }
    }
  }
}

// ---------------- fp32-plane upfirdn2d sampler ----------------
__device__ __forceinline__ float up2x_sample(const float* __restrict__ im, int H, int W,
                                             int oy, int ox)
{
  int my = oy >> 1, mx = ox >> 1;
  int ry0; float ay0, ay1;
  if (oy & 1) { ry0 = my;     ay0 = 0.75f; ay1 = 0.25f; }
  else        { ry0 = my - 1; ay0 = 0.25f; ay1 = 0.75f; }
  int cx0; float bx0, bx1;
  if (ox & 1) { cx0 = mx;     bx0 = 0.75f; bx1 = 0.25f; }
  else        { cx0 = mx - 1; bx0 = 0.25f; bx1 = 0.75f; }
  float v00 = (ry0 >= 0    && cx0 >= 0   ) ? im[ry0 * W + cx0]           : 0.f;
  float v01 = (ry0 >= 0    && cx0 + 1 < W) ? im[ry0 * W + cx0 + 1]       : 0.f;
  float v10 = (ry0 + 1 < H && cx0 >= 0   ) ? im[(ry0 + 1) * W + cx0]     : 0.f;
  float v11 = (ry0 + 1 < H && cx0 + 1 < W) ? im[(ry0 + 1) * W + cx0 + 1] : 0.f;
  return ay0 * (bx0 * v00 + bx1 * v01) + ay1 * (bx0 * v10 + bx1 * v11);
}

// ---------------- img0 = up2x(rgb_fp32) + clip(to_rgb0(x1)) @256^2 ----------------
__global__ void __launch_bounds__(256) img0_kernel(
    const float* __restrict__ rgbf, const unsigned short* __restrict__ x1,
    const float* __restrict__ mt0g, const float* __restrict__ tb,
    float* __restrict__ img0)
{
  __shared__ float mt[768];
  const int tid = threadIdx.x;
  for (int i = tid; i < 768; i += 256) mt[i] = mt0g[i];
  __syncthreads();
  const int p = blockIdx.x * 256 + tid;
  const unsigned short* xp = x1 + (size_t)p * 256;
  float a0 = 0.f, a1 = 0.f, a2 = 0.f;
  for (int i8 = 0; i8 < 32; ++i8) {
    const short8 v = *reinterpret_cast<const short8*>(xp + i8 * 8);
#pragma unroll
    for (int j = 0; j < 8; ++j) {
      const float xv = b2f(v[j]);
      const int ci = i8 * 8 + j;
      a0 = fmaf(mt[ci],       xv, a0);
      a1 = fmaf(mt[256 + ci], xv, a1);
      a2 = fmaf(mt[512 + ci], xv, a2);
    }
  }
  const int oy = p >> 8, ox = p & 255;
  float av[3] = {a0, a1, a2};
#pragma unroll
  for (int o = 0; o < 3; ++o) {
    float y = fminf(fmaxf(av[o] + tb[o], -256.f), 256.f);
    img0[o * 65536 + p] = up2x_sample(rgbf + o * 16384, 128, 128, oy, ox) + y;
  }
}

// ---------------- out = up2x(img0) + clip(sum rgbp + tb) @512^2 ----------------
__global__ void __launch_bounds__(256) final_kernel(
    const float* __restrict__ img0, const float* __restrict__ rgbp,
    const float* __restrict__ tb, float* __restrict__ out)
{
  const int p = blockIdx.x * 256 + threadIdx.x;
  const int oy = p >> 9, ox = p & 511;
#pragma unroll
  for (int o = 0; o < 3; ++o) {
    float a = rgbp[(0 * 3 + o) * 262144 + p] + rgbp[(1 * 3 + o) * 262144 + p];
    float y = fminf(fmaxf(a + tb[o], -256.f), 256.f);
    out[o * 262144 + p] = up2x_sample(img0 + o * 65536, 256, 256, oy, ox) + y;
  }
}

// ---------------- launch ----------------
extern "C" void kernel_launch(void* const* d_in, const int* in_sizes, int n_in,
                              void* d_out, int out_size, void* d_ws, size_t ws_size,
                              hipStream_t stream)
{
  const float* rays   = (const float*)d_in[0];
  const float* rgbs   = (const float*)d_in[1];
  const float* conv_w = (const float*)d_in[2];
  const float* conv_b = (const float*)d_in[3];
  const float* bn_g   = (const float*)d_in[4];
  const float* bn_b   = (const float*)d_in[5];
  const float* bn_m   = (const float*)d_in[6];
  const float* bn_v   = (const float*)d_in[7];
  const float* a0_w   = (const float*)d_in[8];
  const float* a0_b   = (const float*)d_in[9];
  const float* w0     = (const float*)d_in[10];
  const float* b0     = (const float*)d_in[11];
  const float* a1_w   = (const float*)d_in[12];
  const float* a1_b   = (const float*)d_in[13];
  const float* w1     = (const float*)d_in[14];
  const float* b1     = (const float*)d_in[15];
  const float* t0_aw  = (const float*)d_in[16];
  const float* t0_ab  = (const float*)d_in[17];
  const float* t0_w   = (const float*)d_in[18];
  const float* t0_b   = (const float*)d_in[19];
  const float* a2_w   = (const float*)d_in[20];
  const float* a2_b   = (const float*)d_in[21];
  const float* w2     = (const float*)d_in[22];
  const float* b2     = (const float*)d_in[23];
  const float* a3_w   = (const float*)d_in[24];
  const float* a3_b   = (const float*)d_in[25];
  const float* w3     = (const float*)d_in[26];
  const float* b3     = (const float*)d_in[27];
  const float* t1_aw  = (const float*)d_in[28];
  const float* t1_ab  = (const float*)d_in[29];
  const float* t1_w   = (const float*)d_in[30];
  const float* t1_b   = (const float*)d_in[31];

  float* ws  = (float*)d_ws;
  float* out = (float*)d_out;

  unsigned short* wq0   = (unsigned short*)(ws + OFF_WQ0);
  unsigned short* wq1   = (unsigned short*)(ws + OFF_WQ1);
  unsigned short* wq2   = (unsigned short*)(ws + OFF_WQ2);
  unsigned short* wq3   = (unsigned short*)(ws + OFF_WQ3);
  unsigned short* featb = (unsigned short*)(ws + OFF_FEAT);
  unsigned short* ufeat = (unsigned short*)(ws + OFF_UFEAT);
  unsigned short* x0b   = (unsigned short*)(ws + OFF_X0);
  unsigned short* x1b   = (unsigned short*)(ws + OFF_X1);
  unsigned short* x2b   = (unsigned short*)(ws + OFF_X2);
  unsigned short* Ub    = (unsigned short*)(ws + OFF_U);
  const unsigned short* zpage = (const unsigned short*)(ws + OFF_ZERO);

  prep_kernel<<<1, 256, 0, stream>>>(rays, a0_w, a0_b, a1_w, a1_b, t0_aw, t0_ab,
                                     a2_w, a2_b, a3_w, a3_b, t1_aw, t1_ab,
                                     t0_w, t1_w, ws);
  modw_kernel<<<256, 256, 0, stream>>>(w0, ws + OFF_S0, wq0, 32, 256);
  modw_kernel<<<256, 256, 0, stream>>>(w1, ws + OFF_S1, wq1, 256, 256);
  modw_kernel<<<128, 256, 0, stream>>>(w2, ws + OFF_S2, wq2, 256, 128);
  modw_kernel<<<128, 256, 0, stream>>>(w3, ws + OFF_S3, wq3, 128, 128);
  feat_kernel<<<64, 256, 0, stream>>>(rgbs, conv_w, conv_b, bn_g, bn_b, bn_m, bn_v,
                                      featb, ws + OFF_RGBF);
  // up(feat) -> ufeat  (128->256, C=32: c8s=2, w2s=8)
  up2x_nhwc_kernel<<<1024, 256, 0, stream>>>(featb, ufeat, 128, 128, 2, 8);
  // L0: ufeat(32) -> x0(256) @256^2   (2 co-group pairs)
  conv3x3_mfma<false><<<dim3(256, 2), 512, 0, stream>>>(
      ufeat, wq0, b0, x0b, nullptr, nullptr, zpage, 256, 256, 32, 256);
  // L1: x0(256) -> x1(256) @256^2
  conv3x3_mfma<false><<<dim3(256, 2), 512, 0, stream>>>(
      x0b, wq1, b1, x1b, nullptr, nullptr, zpage, 256, 256, 256, 256);
  // img0 = up2x(rgb) + to_rgb0(x1)
  img0_kernel<<<256, 256, 0, stream>>>(ws + OFF_RGBF, x1b, ws + OFF_MT0, t0_b,
                                       ws + OFF_IMG0);
  // up(x1) -> U  (256->512, C=256: c8s=5, w2s=9)
  up2x_nhwc_kernel<<<32768, 256, 0, stream>>>(x1b, Ub, 256, 256, 5, 9);
  // L2: U(256) -> x2(128) @512^2  (both co-groups in one block)
  conv3x3_mfma<false><<<dim3(1024, 1), 512, 0, stream>>>(
      Ub, wq2, b2, x2b, nullptr, nullptr, zpage, 512, 512, 256, 128);
  // L3: x2(128) -> fused to_rgb1 partials @512^2
  conv3x3_mfma<true><<<dim3(1024, 1), 512, 0, stream>>>(
      x2b, wq3, b3, nullptr, ws + OFF_MT1, ws + OFF_RGBP, zpage, 512, 512, 128, 128);
  // out = up2x(img0) + clip(rgbp sum + t1_b)
  final_kernel<<<1024, 256, 0, stream>>>(ws + OFF_IMG0, ws + OFF_RGBP, t1_b, out);
}

// Round 11
// 463.427 us; speedup vs baseline: 2.1054x; 1.0089x over previous
//
#include <hip/hip_runtime.h>
#include <cstddef>

typedef __attribute__((ext_vector_type(8))) short short8;
typedef __attribute__((ext_vector_type(4))) float f32x4;
typedef __attribute__((address_space(3))) void lds_void;
typedef const __attribute__((address_space(1))) void glob_void;

// ---------------- workspace layout (float offsets), total 54525952 f = 208 MiB ------
static const size_t OFF_S0    = 0;         // 32
static const size_t OFF_S1    = 64;        // 256
static const size_t OFF_S2    = 320;       // 256
static const size_t OFF_S3    = 576;       // 128
static const size_t OFF_MT0   = 704;       // 768  fp32 [3][256]
static const size_t OFF_MT1   = 1472;      // 384  fp32 [3][128]
static const size_t OFF_ZERO  = 1856;      // 128 fp32 zeros page (OOB gload_lds target)
static const size_t OFF_RGBF  = 2048;      // 3*128*128 fp32 (skip-path rgb, full precision)
static const size_t OFF_IMG0  = 51200;     // 3*256*256 fp32
static const size_t OFF_RGBP  = 247808;    // 2*3*512*512 fp32 (layer3 fused to_rgb partials)
static const size_t OFF_WQ0   = 1900544;   // bf16 [1][9][256][32]  (slot-swizzled)
static const size_t OFF_WQ1   = 1937408;   // bf16 [8][9][256][32]
static const size_t OFF_WQ2   = 2232320;   // bf16 [8][9][128][32]
static const size_t OFF_WQ3   = 2379776;   // bf16 [4][9][128][32]
static const size_t OFF_FEAT  = 2453504;   // bf16 NHWC [128][128][32]
static const size_t OFF_UFEAT = 2715648;   // bf16 NHWC [256][256][32]
static const size_t OFF_X1    = 4194304;   // bf16 NHWC [256][256][256] (inside X2 region)
static const size_t OFF_X2    = 4194304;   // bf16 NHWC [512][512][128] (overwrites dead x1)
static const size_t OFF_U     = 20971520;  // bf16 NHWC [512][512][256] = 33554432 f
static const size_t OFF_X0    = 20971520;  // bf16 NHWC [256][256][256] (dead before U written)
// timeline: feat->ufeat->L0(x0@U)->L1(x0->x1)->img0(x1)->up(x1->U)->L2(U->x2)->L3(x2->rgbp)->final

__device__ __forceinline__ unsigned short f2bf(float f) {
  unsigned int u = __float_as_uint(f);
  return (unsigned short)((u + 0x7FFFu + ((u >> 16) & 1u)) >> 16);
}
__device__ __forceinline__ float b2f(short h) {
  return __uint_as_float(((unsigned int)(unsigned short)h) << 16);
}

// ---------------- prep: w_vec, styles, to_rgb modulated weights (fp32) ----------------
__global__ void __launch_bounds__(256) prep_kernel(
    const float* __restrict__ rays,
    const float* __restrict__ a0w, const float* __restrict__ a0b,
    const float* __restrict__ a1w, const float* __restrict__ a1b,
    const float* __restrict__ t0aw, const float* __restrict__ t0ab,
    const float* __restrict__ a2w, const float* __restrict__ a2b,
    const float* __restrict__ a3w, const float* __restrict__ a3b,
    const float* __restrict__ t1aw, const float* __restrict__ t1ab,
    const float* __restrict__ t0w, const float* __restrict__ t1w,
    float* __restrict__ ws)
{
  __shared__ float wv[72];
  __shared__ float st0l[256];
  __shared__ float st1l[128];
  const int tid = threadIdx.x;
  if (tid < 128) ws[OFF_ZERO + tid] = 0.f;   // zeros page for OOB gload_lds
  if (tid < 36) {
    int i = tid / 12, j = tid % 12;
    float v = rays[i * 16384] * (float)(1 << j);
    wv[tid]      = sinf(v);
    wv[36 + tid] = cosf(v);
  }
  __syncthreads();
  const float inv72 = 0.11785113019775793f;   // 1/sqrt(72)

  if (tid < 32) {
    float d = 0.f;
    for (int k = 0; k < 72; ++k) d += wv[k] * a0w[tid * 72 + k];
    ws[OFF_S0 + tid] = fmaf(d, inv72, a0b[tid]);
  }
  {
    float d = 0.f;
    for (int k = 0; k < 72; ++k) d += wv[k] * a1w[tid * 72 + k];
    ws[OFF_S1 + tid] = fmaf(d, inv72, a1b[tid]);
  }
  {
    float d = 0.f;
    for (int k = 0; k < 72; ++k) d += wv[k] * t0aw[tid * 72 + k];
    st0l[tid] = fmaf(d, inv72, t0ab[tid]) * 0.0625f;       // /sqrt(256)
  }
  {
    float d = 0.f;
    for (int k = 0; k < 72; ++k) d += wv[k] * a2w[tid * 72 + k];
    ws[OFF_S2 + tid] = fmaf(d, inv72, a2b[tid]);
  }
  if (tid < 128) {
    float d = 0.f;
    for (int k = 0; k < 72; ++k) d += wv[k] * a3w[tid * 72 + k];
    ws[OFF_S3 + tid] = fmaf(d, inv72, a3b[tid]);
  }
  if (tid < 128) {
    float d = 0.f;
    for (int k = 0; k < 72; ++k) d += wv[k] * t1aw[tid * 72 + k];
    st1l[tid] = fmaf(d, inv72, t1ab[tid]) * 0.08838834764831845f;  // /sqrt(128)
  }
  __syncthreads();
  for (int i = tid; i < 768; i += 256) ws[OFF_MT0 + i] = t0w[i] * st0l[i & 255];
  for (int i = tid; i < 384; i += 256) ws[OFF_MT1 + i] = t1w[i] * st1l[i & 127];
}

// ------ weight modulate + demodulate -> bf16 [ci/32][tap][Co][slot-swizzled 32] ------
// Within each co-row of 32 k (4 slots of 8), store slot at  sl ^ (co&3) ^ ((co>>2)&3)
// so a LINEAR global_load_lds stage + XOR read is bank-balanced (2-way, free).
__global__ void __launch_bounds__(256) modw_kernel(
    const float* __restrict__ w, const float* __restrict__ s,
    unsigned short* __restrict__ wq, int Ci, int Co)
{
  const int co = blockIdx.x;
  const int n = Ci * 9;
  float local = 0.f;
  for (int i = threadIdx.x; i < n; i += 256) {
    float v = w[co * n + i] * s[i / 9];
    local += v * v;
  }
#pragma unroll
  for (int off = 32; off >= 1; off >>= 1) local += __shfl_xor(local, off);
  __shared__ float red[4];
  if ((threadIdx.x & 63) == 0) red[threadIdx.x >> 6] = local;
  __syncthreads();
  const float d = rsqrtf(red[0] + red[1] + red[2] + red[3] + 1e-8f);
  const int sxor = (co & 3) ^ ((co >> 2) & 3);
  for (int i = threadIdx.x; i < n; i += 256) {
    int ci = i / 9, t = i - ci * 9;
    int kk = ci & 31;
    int sl = (kk >> 3) ^ sxor;
    wq[(((size_t)(ci >> 5) * 9 + t) * Co + co) * 32 + (sl << 3) + (kk & 7)] =
        f2bf(w[co * n + i] * s[ci] * d);
  }
}

// ---------- feat: conv1x1 3->32 + relu + bn @128^2 -> NHWC bf16 + fp32 rgb planes -----
__global__ void __launch_bounds__(256) feat_kernel(
    const float* __restrict__ rgbs, const float* __restrict__ cw, const float* __restrict__ cb,
    const float* __restrict__ gam, const float* __restrict__ bet,
    const float* __restrict__ mean, const float* __restrict__ var,
    unsigned short* __restrict__ feat, float* __restrict__ rgbf)
{
  const int p = blockIdx.x * 256 + threadIdx.x;
  const float r = rgbs[p], g = rgbs[16384 + p], b = rgbs[32768 + p];
  unsigned int pk[16];
#pragma unroll
  for (int co = 0; co < 32; ++co) {
    float v = cw[co * 3] * r + cw[co * 3 + 1] * g + cw[co * 3 + 2] * b + cb[co];
    v = fmaxf(v, 0.f);
    float inv = rsqrtf(var[co] + 1e-5f);
    v = (v - mean[co]) * (inv * gam[co]) + bet[co];
    if (co < 3) rgbf[co * 16384 + p] = v;
    unsigned int h = f2bf(v);
    if ((co & 1) == 0) pk[co >> 1] = h;
    else               pk[co >> 1] |= h << 16;
  }
  uint4* dst = reinterpret_cast<uint4*>(feat + (size_t)p * 32);
#pragma unroll
  for (int q = 0; q < 4; ++q)
    dst[q] = make_uint4(pk[q * 4], pk[q * 4 + 1], pk[q * 4 + 2], pk[q * 4 + 3]);
}

// ---------------- NHWC bf16 2x antialiased upsample ----------------
__global__ void __launch_bounds__(256) up2x_nhwc_kernel(
    const unsigned short* __restrict__ in, unsigned short* __restrict__ out,
    int H, int W, int c8s /*log2(C/8)*/, int w2s /*log2(2W)*/)
{
  const int cid = blockIdx.x * 256 + threadIdx.x;
  const int k = cid & ((1 << c8s) - 1);
  const int pix = cid >> c8s;
  const int ey = pix >> w2s;
  const int ex = pix & ((1 << w2s) - 1);
  const int C = 8 << c8s;
  int ry0; float ay0, ay1;
  if (ey & 1) { ry0 = ey >> 1;       ay0 = 0.75f; ay1 = 0.25f; }
  else        { ry0 = (ey >> 1) - 1; ay0 = 0.25f; ay1 = 0.75f; }
  int cx0; float bx0, bx1;
  if (ex & 1) { cx0 = ex >> 1;       bx0 = 0.75f; bx1 = 0.25f; }
  else        { cx0 = (ex >> 1) - 1; bx0 = 0.25f; bx1 = 0.75f; }
  const short8 z = {0, 0, 0, 0, 0, 0, 0, 0};
  short8 v00 = z, v01 = z, v10 = z, v11 = z;
  const bool yo0 = (ry0 >= 0), yo1 = (ry0 + 1 < H);
  const bool xo0 = (cx0 >= 0), xo1 = (cx0 + 1 < W);
  if (yo0 && xo0) v00 = *reinterpret_cast<const short8*>(in + ((size_t)(ry0 * W + cx0) * C + k * 8));
  if (yo0 && xo1) v01 = *reinterpret_cast<const short8*>(in + ((size_t)(ry0 * W + cx0 + 1) * C + k * 8));
  if (yo1 && xo0) v10 = *reinterpret_cast<const short8*>(in + ((size_t)((ry0 + 1) * W + cx0) * C + k * 8));
  if (yo1 && xo1) v11 = *reinterpret_cast<const short8*>(in + ((size_t)((ry0 + 1) * W + cx0 + 1) * C + k * 8));
  unsigned int o[4];
#pragma unroll
  for (int j = 0; j < 8; ++j) {
    float f = ay0 * (bx0 * b2f(v00[j]) + bx1 * b2f(v01[j]))
            + ay1 * (bx0 * b2f(v10[j]) + bx1 * b2f(v11[j]));
    unsigned int h = f2bf(f);
    if ((j & 1) == 0) o[j >> 1] = h;
    else              o[j >> 1] |= h << 16;
  }
  *reinterpret_cast<uint4*>(out + (size_t)pix * C + k * 8) = make_uint4(o[0], o[1], o[2], o[3]);
}

// ---------------- conv3x3 via MFMA implicit GEMM (NHWC bf16) ----------------
// Block: 8 waves (512 thr), 16x16 pixel tile, TWO 64-co groups (block = 128-co slice,
// cogB = blockIdx.y*128). Waves 0-3 -> co-group 0, 4-7 -> group 1; rows (wv&3)*4.
// WEIGHTS ARE LDS-STAGED: per 3-tap group (kx-major: taps {kx, kx+3, kx+6}), 24 KB
// staged linearly via global_load_lds into a 2-deep ring; A-fragment reads are
// ds_read_b128 (lgkmcnt) -> decoupled from activation staging (vmcnt), which now
// drains only at barriers with a full tap-group of compute cover.
// B: kx-major rolling 4-register window (18 ds_read/chunk).  3 barriers/chunk.
template <bool FUSE_RGB>
__global__ void __launch_bounds__(512) conv3x3_mfma(
    const unsigned short* __restrict__ in,   // [H][W][Ci] bf16
    const unsigned short* __restrict__ wq,   // [Ci/32][9][Co][32] bf16 (slot-swizzled)
    const float* __restrict__ bias,          // [Co]
    unsigned short* __restrict__ out,        // [H][W][Co] bf16 (or null)
    const float* __restrict__ rgbw,          // [3][Co] fp32 (FUSE)
    float* __restrict__ rgbp,                // [2][3][H*W] fp32 (FUSE)
    const unsigned short* __restrict__ zpage,// >=512B of zeros
    int H, int W, int Ci, int Co)
{
  const int tid  = threadIdx.x;
  const int lane = tid & 63;
  const int wv   = tid >> 6;          // 0..7
  const int wr   = wv & 3;            // row group within tile
  const int wg   = wv >> 2;           // co-group within block (0/1)
  const int lo   = lane & 15, hi = lane >> 4;
  const int tpr  = W >> 4;
  const int T_y  = (blockIdx.x / tpr) << 4;
  const int T_x  = (blockIdx.x % tpr) << 4;
  const int cogB = blockIdx.y << 7;   // block's 128-co weight slice
  const int cog  = cogB + (wg << 6);

  __shared__ short8 xs[2][1296];      // act dbuf [pix 18*18][4 k-slots]
  __shared__ short8 wlds[2][1536];    // weight ring [buf][ky 3][co 128][slot 4]
  __shared__ float  rw[FUSE_RGB ? 384 : 4];

  if (FUSE_RGB) {
    for (int i = tid; i < 3 * Co; i += 512) rw[i] = rgbw[i];
  }

  f32x4 acc[4][4];
#pragma unroll
  for (int a = 0; a < 4; ++a)
#pragma unroll
    for (int b = 0; b < 4; ++b) acc[a][b] = (f32x4){0.f, 0.f, 0.f, 0.f};

  // ---- ci-invariant act staging sources (slot = j*512 + tid, linear) ----
  const unsigned short* gsrc[3];
#pragma unroll
  for (int j = 0; j < 3; ++j) {
    const int s = j * 512 + tid;
    const int pix = s >> 2, kslot = s & 3;
    const int rr = pix / 18, cc = pix - rr * 18;
    const int gy = T_y - 1 + rr, gx = T_x - 1 + cc;
    const int k = kslot ^ ((cc >> 1) & 3);      // inverse swizzle on the SOURCE
    const bool inb = (s < 1296) && gy >= 0 && gy < H && gx >= 0 && gx < W;
    gsrc[j] = inb ? (in + ((size_t)(gy * W + gx) * Ci + (k << 3))) : zpage;
  }

#define STAGE(c, buf)                                                              \
  {                                                                                \
    const int cb_ = (c) << 5;                                                      \
    _Pragma("unroll")                                                              \
    for (int j = 0; j < 2; ++j)                                                    \
      __builtin_amdgcn_global_load_lds((glob_void*)(gsrc[j] + cb_),                \
                                       (lds_void*)&xs[buf][j * 512 + tid], 16, 0, 0); \
    if (tid < 272)                                                                 \
      __builtin_amdgcn_global_load_lds((glob_void*)(gsrc[2] + cb_),                \
                                       (lds_void*)&xs[buf][1024 + tid], 16, 0, 0); \
  }

  // weight group stage: taps {KX, KX+3, KX+6} of chunk C -> wlds[BUF], linear copy
#define STAGE_W(C, KX, BUF)                                                        \
  {                                                                                \
    _Pragma("unroll")                                                              \
    for (int j = 0; j < 3; ++j) {                                                  \
      const unsigned short* src_ =                                                 \
          wq + ((size_t)((C) * 9 + j * 3 + (KX)) * Co + cogB) * 32 + tid * 8;      \
      __builtin_amdgcn_global_load_lds((glob_void*)src_,                           \
                                       (lds_void*)&wlds[BUF][(j << 9) + tid], 16, 0, 0); \
    }                                                                              \
  }

  // A-fragment read from wlds: co_blk = wg*64+cf*16+lo, slot = hi ^ sxa
  const int sxa   = (lo & 3) ^ ((lo >> 2) & 3);
  const int wbase = (((wg << 6) + lo) << 2) + (hi ^ sxa);
#define ALOADW(SLOT, KY, BUF)                                                      \
  {                                                                                \
    _Pragma("unroll")                                                              \
    for (int cf = 0; cf < 4; ++cf)                                                 \
      apf[SLOT][cf] = wlds[BUF][((KY) << 9) + wbase + (cf << 6)];                  \
  }

  // prologue: stage act chunk 0 + weight group (c=0, kx=0)
  STAGE(0, 0);
  STAGE_W(0, 0, 0);
  __syncthreads();

  const int nch = Ci >> 5;
  const int rstride = 72;   // 18*4 short8 per tile row
  int wb = 0;
  for (int c = 0; c < nch; ++c) {
    const int cur = c & 1;
#pragma unroll
    for (int g = 0; g < 3; ++g) {            // g = kx
      // issue next weight-group staging (vmcnt; drained at this group's barrier)
      if (g < 2)             { STAGE_W(c, g + 1, wb ^ 1); }
      else if (c + 1 < nch)  { STAGE_W(c + 1, 0, wb ^ 1); }
      if (g == 0 && c + 1 < nch) STAGE(c + 1, cur ^ 1);

      const int tx2  = lo + g;
      const int xv_  = hi ^ ((tx2 >> 1) & 3);
      const int rowb = (((wr << 2) * 18 + tx2) << 2) + xv_;
      short8 b0 = xs[cur][rowb];
      short8 b1 = xs[cur][rowb + rstride];
      short8 b2 = xs[cur][rowb + 2 * rstride];
      short8 b3 = xs[cur][rowb + 3 * rstride];

      short8 apf[2][4];
      ALOADW(0, 0, wb);
      ALOADW(1, 1, wb);
      // ky = 0: rows r+0 -> b0..b3
#pragma unroll
      for (int cf = 0; cf < 4; ++cf) {
        acc[cf][0] = __builtin_amdgcn_mfma_f32_16x16x32_bf16(apf[0][cf], b0, acc[cf][0], 0, 0, 0);
        acc[cf][1] = __builtin_amdgcn_mfma_f32_16x16x32_bf16(apf[0][cf], b1, acc[cf][1], 0, 0, 0);
        acc[cf][2] = __builtin_amdgcn_mfma_f32_16x16x32_bf16(apf[0][cf], b2, acc[cf][2], 0, 0, 0);
        acc[cf][3] = __builtin_amdgcn_mfma_f32_16x16x32_bf16(apf[0][cf], b3, acc[cf][3], 0, 0, 0);
      }
      // ky = 1: rows r+1 -> b1,b2,b3,(new)b0
      b0 = xs[cur][rowb + 4 * rstride];
      ALOADW(0, 2, wb);
#pragma unroll
      for (int cf = 0; cf < 4; ++cf) {
        acc[cf][0] = __builtin_amdgcn_mfma_f32_16x16x32_bf16(apf[1][cf], b1, acc[cf][0], 0, 0, 0);
        acc[cf][1] = __builtin_amdgcn_mfma_f32_16x16x32_bf16(apf[1][cf], b2, acc[cf][1], 0, 0, 0);
        acc[cf][2] = __builtin_amdgcn_mfma_f32_16x16x32_bf16(apf[1][cf], b3, acc[cf][2], 0, 0, 0);
        acc[cf][3] = __builtin_amdgcn_mfma_f32_16x16x32_bf16(apf[1][cf], b0, acc[cf][3], 0, 0, 0);
      }
      // ky = 2: rows r+2 -> b2,b3,b0,(new)b1
      b1 = xs[cur][rowb + 5 * rstride];
#pragma unroll
      for (int cf = 0; cf < 4; ++cf) {
        acc[cf][0] = __builtin_amdgcn_mfma_f32_16x16x32_bf16(apf[0][cf], b2, acc[cf][0], 0, 0, 0);
        acc[cf][1] = __builtin_amdgcn_mfma_f32_16x16x32_bf16(apf[0][cf], b3, acc[cf][1], 0, 0, 0);
        acc[cf][2] = __builtin_amdgcn_mfma_f32_16x16x32_bf16(apf[0][cf], b0, acc[cf][2], 0, 0, 0);
        acc[cf][3] = __builtin_amdgcn_mfma_f32_16x16x32_bf16(apf[0][cf], b1, acc[cf][3], 0, 0, 0);
      }
      __syncthreads();     // publishes wlds[wb^1] (+ act at g==0); readers of wb done
      wb ^= 1;
    }
  }
#undef STAGE
#undef STAGE_W
#undef ALOADW

  // ---- epilogue ----
  const float rt2 = 1.41421356237309515f;
#pragma unroll
  for (int r = 0; r < 4; ++r) {
    const int gy = T_y + (wr << 2) + r;
    const int gx = T_x + lo;
    if (!FUSE_RGB) {
#pragma unroll
      for (int cf = 0; cf < 4; ++cf) {
        const int cb = cog + (cf << 4) + (hi << 2);
        const f32x4 bi = *reinterpret_cast<const f32x4*>(bias + cb);
        unsigned short h[4];
#pragma unroll
        for (int reg = 0; reg < 4; ++reg) {
          float vv = acc[cf][r][reg] + bi[reg];
          vv = (vv >= 0.f) ? vv : 0.2f * vv;
          vv *= rt2;
          vv = fminf(fmaxf(vv, -256.f), 256.f);
          h[reg] = f2bf(vv);
        }
        uint2 pk;
        pk.x = (unsigned int)h[0] | ((unsigned int)h[1] << 16);
        pk.y = (unsigned int)h[2] | ((unsigned int)h[3] << 16);
        *reinterpret_cast<uint2*>(out + (size_t)(gy * W + gx) * Co + cb) = pk;
      }
    } else {
      float p0 = 0.f, p1 = 0.f, p2 = 0.f;
#pragma unroll
      for (int cf = 0; cf < 4; ++cf) {
        const int cb = cog + (cf << 4) + (hi << 2);
        const f32x4 bi = *reinterpret_cast<const f32x4*>(bias + cb);
#pragma unroll
        for (int reg = 0; reg < 4; ++reg) {
          float vv = acc[cf][r][reg] + bi[reg];
          vv = (vv >= 0.f) ? vv : 0.2f * vv;
          vv *= rt2;
          vv = fminf(fmaxf(vv, -256.f), 256.f);
          p0 = fmaf(rw[cb + reg], vv, p0);
          p1 = fmaf(rw[Co + cb + reg], vv, p1);
          p2 = fmaf(rw[2 * Co + cb + reg], vv, p2);
        }
      }
      p0 += __shfl_xor(p0, 16); p0 += __shfl_xor(p0, 32);
      p1 += __shfl_xor(p1, 16); p1 += __shfl_xor(p1, 32);
      p2 += __shfl_xor(p2, 16); p2 += __shfl_xor(p2, 32);
      if (hi == 0) {
        const size_t HWs = (size_t)H * W;
        const size_t px  = (size_t)gy * W + gx;
        rgbp[((size_t)wg * 3 + 0) * HWs + px] = p0;
        rgbp[((size_t)wg * 3 + 1) * HWs + px] = p1;
        rgbp[((size_t)wg * 3 + 2) * HWs + px] = p2;
      }
    }
  }
}

// ---------------- fp32-plane upfirdn2d sampler ----------------
__device__ __forceinline__ float up2x_sample(const float* __restrict__ im, int H, int W,
                                             int oy, int ox)
{
  int my = oy >> 1, mx = ox >> 1;
  int ry0; float ay0, ay1;
  if (oy & 1) { ry0 = my;     ay0 = 0.75f; ay1 = 0.25f; }
  else        { ry0 = my - 1; ay0 = 0.25f; ay1 = 0.75f; }
  int cx0; float bx0, bx1;
  if (ox & 1) { cx0 = mx;     bx0 = 0.75f; bx1 = 0.25f; }
  else        { cx0 = mx - 1; bx0 = 0.25f; bx1 = 0.75f; }
  float v00 = (ry0 >= 0    && cx0 >= 0   ) ? im[ry0 * W + cx0]           : 0.f;
  float v01 = (ry0 >= 0    && cx0 + 1 < W) ? im[ry0 * W + cx0 + 1]       : 0.f;
  float v10 = (ry0 + 1 < H && cx0 >= 0   ) ? im[(ry0 + 1) * W + cx0]     : 0.f;
  float v11 = (ry0 + 1 < H && cx0 + 1 < W) ? im[(ry0 + 1) * W + cx0 + 1] : 0.f;
  return ay0 * (bx0 * v00 + bx1 * v01) + ay1 * (bx0 * v10 + bx1 * v11);
}

// ---------------- img0 = up2x(rgb_fp32) + clip(to_rgb0(x1)) @256^2 ----------------
__global__ void __launch_bounds__(256) img0_kernel(
    const float* __restrict__ rgbf, const unsigned short* __restrict__ x1,
    const float* __restrict__ mt0g, const float* __restrict__ tb,
    float* __restrict__ img0)
{
  __shared__ float mt[768];
  const int tid = threadIdx.x;
  for (int i = tid; i < 768; i += 256) mt[i] = mt0g[i];
  __syncthreads();
  const int p = blockIdx.x * 256 + tid;
  const unsigned short* xp = x1 + (size_t)p * 256;
  float a0 = 0.f, a1 = 0.f, a2 = 0.f;
  for (int i8 = 0; i8 < 32; ++i8) {
    const short8 v = *reinterpret_cast<const short8*>(xp + i8 * 8);
#pragma unroll
    for (int j = 0; j < 8; ++j) {
      const float xv = b2f(v[j]);
      const int ci = i8 * 8 + j;
      a0 = fmaf(mt[ci],       xv, a0);
      a1 = fmaf(mt[256 + ci], xv, a1);
      a2 = fmaf(mt[512 + ci], xv, a2);
    }
  }
  const int oy = p >> 8, ox = p & 255;
  float av[3] = {a0, a1, a2};
#pragma unroll
  for (int o = 0; o < 3; ++o) {
    float y = fminf(fmaxf(av[o] + tb[o], -256.f), 256.f);
    img0[o * 65536 + p] = up2x_sample(rgbf + o * 16384, 128, 128, oy, ox) + y;
  }
}

// ---------------- out = up2x(img0) + clip(sum rgbp + tb) @512^2 ----------------
__global__ void __launch_bounds__(256) final_kernel(
    const float* __restrict__ img0, const float* __restrict__ rgbp,
    const float* __restrict__ tb, float* __restrict__ out)
{
  const int p = blockIdx.x * 256 + threadIdx.x;
  const int oy = p >> 9, ox = p & 511;
#pragma unroll
  for (int o = 0; o < 3; ++o) {
    float a = rgbp[(0 * 3 + o) * 262144 + p] + rgbp[(1 * 3 + o) * 262144 + p];
    float y = fminf(fmaxf(a + tb[o], -256.f), 256.f);
    out[o * 262144 + p] = up2x_sample(img0 + o * 65536, 256, 256, oy, ox) + y;
  }
}

// ---------------- launch ----------------
extern "C" void kernel_launch(void* const* d_in, const int* in_sizes, int n_in,
                              void* d_out, int out_size, void* d_ws, size_t ws_size,
                              hipStream_t stream)
{
  const float* rays   = (const float*)d_in[0];
  const float* rgbs   = (const float*)d_in[1];
  const float* conv_w = (const float*)d_in[2];
  const float* conv_b = (const float*)d_in[3];
  const float* bn_g   = (const float*)d_in[4];
  const float* bn_b   = (const float*)d_in[5];
  const float* bn_m   = (const float*)d_in[6];
  const float* bn_v   = (const float*)d_in[7];
  const float* a0_w   = (const float*)d_in[8];
  const float* a0_b   = (const float*)d_in[9];
  const float* w0     = (const float*)d_in[10];
  const float* b0     = (const float*)d_in[11];
  const float* a1_w   = (const float*)d_in[12];
  const float* a1_b   = (const float*)d_in[13];
  const float* w1     = (const float*)d_in[14];
  const float* b1     = (const float*)d_in[15];
  const float* t0_aw  = (const float*)d_in[16];
  const float* t0_ab  = (const float*)d_in[17];
  const float* t0_w   = (const float*)d_in[18];
  const float* t0_b   = (const float*)d_in[19];
  const float* a2_w   = (const float*)d_in[20];
  const float* a2_b   = (const float*)d_in[21];
  const float* w2     = (const float*)d_in[22];
  const float* b2     = (const float*)d_in[23];
  const float* a3_w   = (const float*)d_in[24];
  const float* a3_b   = (const float*)d_in[25];
  const float* w3     = (const float*)d_in[26];
  const float* b3     = (const float*)d_in[27];
  const float* t1_aw  = (const float*)d_in[28];
  const float* t1_ab  = (const float*)d_in[29];
  const float* t1_w   = (const float*)d_in[30];
  const float* t1_b   = (const float*)d_in[31];

  float* ws  = (float*)d_ws;
  float* out = (float*)d_out;

  unsigned short* wq0   = (unsigned short*)(ws + OFF_WQ0);
  unsigned short* wq1   = (unsigned short*)(ws + OFF_WQ1);
  unsigned short* wq2   = (unsigned short*)(ws + OFF_WQ2);
  unsigned short* wq3   = (unsigned short*)(ws + OFF_WQ3);
  unsigned short* featb = (unsigned short*)(ws + OFF_FEAT);
  unsigned short* ufeat = (unsigned short*)(ws + OFF_UFEAT);
  unsigned short* x0b   = (unsigned short*)(ws + OFF_X0);
  unsigned short* x1b   = (unsigned short*)(ws + OFF_X1);
  unsigned short* x2b   = (unsigned short*)(ws + OFF_X2);
  unsigned short* Ub    = (unsigned short*)(ws + OFF_U);
  const unsigned short* zpage = (const unsigned short*)(ws + OFF_ZERO);

  prep_kernel<<<1, 256, 0, stream>>>(rays, a0_w, a0_b, a1_w, a1_b, t0_aw, t0_ab,
                                     a2_w, a2_b, a3_w, a3_b, t1_aw, t1_ab,
                                     t0_w, t1_w, ws);
  modw_kernel<<<256, 256, 0, stream>>>(w0, ws + OFF_S0, wq0, 32, 256);
  modw_kernel<<<256, 256, 0, stream>>>(w1, ws + OFF_S1, wq1, 256, 256);
  modw_kernel<<<128, 256, 0, stream>>>(w2, ws + OFF_S2, wq2, 256, 128);
  modw_kernel<<<128, 256, 0, stream>>>(w3, ws + OFF_S3, wq3, 128, 128);
  feat_kernel<<<64, 256, 0, stream>>>(rgbs, conv_w, conv_b, bn_g, bn_b, bn_m, bn_v,
                                      featb, ws + OFF_RGBF);
  // up(feat) -> ufeat  (128->256, C=32: c8s=2, w2s=8)
  up2x_nhwc_kernel<<<1024, 256, 0, stream>>>(featb, ufeat, 128, 128, 2, 8);
  // L0: ufeat(32) -> x0(256) @256^2   (2 co-slices of 128)
  conv3x3_mfma<false><<<dim3(256, 2), 512, 0, stream>>>(
      ufeat, wq0, b0, x0b, nullptr, nullptr, zpage, 256, 256, 32, 256);
  // L1: x0(256) -> x1(256) @256^2
  conv3x3_mfma<false><<<dim3(256, 2), 512, 0, stream>>>(
      x0b, wq1, b1, x1b, nullptr, nullptr, zpage, 256, 256, 256, 256);
  // img0 = up2x(rgb) + to_rgb0(x1)
  img0_kernel<<<256, 256, 0, stream>>>(ws + OFF_RGBF, x1b, ws + OFF_MT0, t0_b,
                                       ws + OFF_IMG0);
  // up(x1) -> U  (256->512, C=256: c8s=5, w2s=9)
  up2x_nhwc_kernel<<<32768, 256, 0, stream>>>(x1b, Ub, 256, 256, 5, 9);
  // L2: U(256) -> x2(128) @512^2  (single 128-co slice)
  conv3x3_mfma<false><<<dim3(1024, 1), 512, 0, stream>>>(
      Ub, wq2, b2, x2b, nullptr, nullptr, zpage, 512, 512, 256, 128);
  // L3: x2(128) -> fused to_rgb1 partials @512^2
  conv3x3_mfma<true><<<dim3(1024, 1), 512, 0, stream>>>(
      x2b, wq3, b3, nullptr, ws + OFF_MT1, ws + OFF_RGBP, zpage, 512, 512, 128, 128);
  // out = up2x(img0) + clip(rgbp sum + t1_b)
  final_kernel<<<1024, 256, 0, stream>>>(ws + OFF_IMG0, ws + OFF_RGBP, t1_b, out);
}

// Round 12
// 409.538 us; speedup vs baseline: 2.3825x; 1.1316x over previous
//
#include <hip/hip_runtime.h>
#include <cstddef>

typedef __attribute__((ext_vector_type(8))) short short8;
typedef __attribute__((ext_vector_type(4))) float f32x4;
typedef __attribute__((address_space(3))) void lds_void;
typedef const __attribute__((address_space(1))) void glob_void;

// ---------------- workspace layout (float offsets), total 54525952 f = 208 MiB ------
static const size_t OFF_S0    = 0;         // 32
static const size_t OFF_S1    = 64;        // 256
static const size_t OFF_S2    = 320;       // 256
static const size_t OFF_S3    = 576;       // 128
static const size_t OFF_MT0   = 704;       // 768  fp32 [3][256]
static const size_t OFF_MT1   = 1472;      // 384  fp32 [3][128]
static const size_t OFF_ZERO  = 1856;      // 128 fp32 zeros page (OOB gload_lds target)
static const size_t OFF_RGBF  = 2048;      // 3*128*128 fp32 (skip-path rgb, full precision)
static const size_t OFF_IMG0  = 51200;     // 3*256*256 fp32
static const size_t OFF_RGBP  = 247808;    // 2*3*512*512 fp32 (layer3 fused to_rgb partials)
static const size_t OFF_WQ0   = 1900544;   // bf16 [1][9][256][32]  (slot-swizzled)
static const size_t OFF_WQ1   = 1937408;   // bf16 [8][9][256][32]
static const size_t OFF_WQ2   = 2232320;   // bf16 [8][9][128][32]
static const size_t OFF_WQ3   = 2379776;   // bf16 [4][9][128][32]
static const size_t OFF_FEAT  = 2453504;   // bf16 NHWC [128][128][32]
static const size_t OFF_UFEAT = 2715648;   // bf16 NHWC [256][256][32]
static const size_t OFF_X1    = 4194304;   // bf16 NHWC [256][256][256] (inside X2 region)
static const size_t OFF_X2    = 4194304;   // bf16 NHWC [512][512][128] (overwrites dead x1)
static const size_t OFF_U     = 20971520;  // bf16 NHWC [512][512][256] = 33554432 f
static const size_t OFF_X0    = 20971520;  // bf16 NHWC [256][256][256] (dead before U written)
// timeline: feat->ufeat->L0(x0@U)->L1(x0->x1)->img0(x1)->up(x1->U)->L2(U->x2)->L3(x2->rgbp)->final

__device__ __forceinline__ unsigned short f2bf(float f) {
  unsigned int u = __float_as_uint(f);
  return (unsigned short)((u + 0x7FFFu + ((u >> 16) & 1u)) >> 16);
}
__device__ __forceinline__ float b2f(short h) {
  return __uint_as_float(((unsigned int)(unsigned short)h) << 16);
}

// ---------------- prep: w_vec, styles, to_rgb modulated weights (fp32) ----------------
__global__ void __launch_bounds__(256) prep_kernel(
    const float* __restrict__ rays,
    const float* __restrict__ a0w, const float* __restrict__ a0b,
    const float* __restrict__ a1w, const float* __restrict__ a1b,
    const float* __restrict__ t0aw, const float* __restrict__ t0ab,
    const float* __restrict__ a2w, const float* __restrict__ a2b,
    const float* __restrict__ a3w, const float* __restrict__ a3b,
    const float* __restrict__ t1aw, const float* __restrict__ t1ab,
    const float* __restrict__ t0w, const float* __restrict__ t1w,
    float* __restrict__ ws)
{
  __shared__ float wv[72];
  __shared__ float st0l[256];
  __shared__ float st1l[128];
  const int tid = threadIdx.x;
  if (tid < 128) ws[OFF_ZERO + tid] = 0.f;   // zeros page for OOB gload_lds
  if (tid < 36) {
    int i = tid / 12, j = tid % 12;
    float v = rays[i * 16384] * (float)(1 << j);
    wv[tid]      = sinf(v);
    wv[36 + tid] = cosf(v);
  }
  __syncthreads();
  const float inv72 = 0.11785113019775793f;   // 1/sqrt(72)

  if (tid < 32) {
    float d = 0.f;
    for (int k = 0; k < 72; ++k) d += wv[k] * a0w[tid * 72 + k];
    ws[OFF_S0 + tid] = fmaf(d, inv72, a0b[tid]);
  }
  {
    float d = 0.f;
    for (int k = 0; k < 72; ++k) d += wv[k] * a1w[tid * 72 + k];
    ws[OFF_S1 + tid] = fmaf(d, inv72, a1b[tid]);
  }
  {
    float d = 0.f;
    for (int k = 0; k < 72; ++k) d += wv[k] * t0aw[tid * 72 + k];
    st0l[tid] = fmaf(d, inv72, t0ab[tid]) * 0.0625f;       // /sqrt(256)
  }
  {
    float d = 0.f;
    for (int k = 0; k < 72; ++k) d += wv[k] * a2w[tid * 72 + k];
    ws[OFF_S2 + tid] = fmaf(d, inv72, a2b[tid]);
  }
  if (tid < 128) {
    float d = 0.f;
    for (int k = 0; k < 72; ++k) d += wv[k] * a3w[tid * 72 + k];
    ws[OFF_S3 + tid] = fmaf(d, inv72, a3b[tid]);
  }
  if (tid < 128) {
    float d = 0.f;
    for (int k = 0; k < 72; ++k) d += wv[k] * t1aw[tid * 72 + k];
    st1l[tid] = fmaf(d, inv72, t1ab[tid]) * 0.08838834764831845f;  // /sqrt(128)
  }
  __syncthreads();
  for (int i = tid; i < 768; i += 256) ws[OFF_MT0 + i] = t0w[i] * st0l[i & 255];
  for (int i = tid; i < 384; i += 256) ws[OFF_MT1 + i] = t1w[i] * st1l[i & 127];
}

// ------ weight modulate + demodulate -> bf16 [ci/32][tap][Co][slot-swizzled 32] ------
// Within each co-row of 32 k (4 slots of 8), store slot at  sl ^ (co&3) ^ ((co>>2)&3)
// so a LINEAR global_load_lds stage + XOR read is bank-balanced.
__global__ void __launch_bounds__(256) modw_kernel(
    const float* __restrict__ w, const float* __restrict__ s,
    unsigned short* __restrict__ wq, int Ci, int Co)
{
  const int co = blockIdx.x;
  const int n = Ci * 9;
  float local = 0.f;
  for (int i = threadIdx.x; i < n; i += 256) {
    float v = w[co * n + i] * s[i / 9];
    local += v * v;
  }
#pragma unroll
  for (int off = 32; off >= 1; off >>= 1) local += __shfl_xor(local, off);
  __shared__ float red[4];
  if ((threadIdx.x & 63) == 0) red[threadIdx.x >> 6] = local;
  __syncthreads();
  const float d = rsqrtf(red[0] + red[1] + red[2] + red[3] + 1e-8f);
  const int sxor = (co & 3) ^ ((co >> 2) & 3);
  for (int i = threadIdx.x; i < n; i += 256) {
    int ci = i / 9, t = i - ci * 9;
    int kk = ci & 31;
    int sl = (kk >> 3) ^ sxor;
    wq[(((size_t)(ci >> 5) * 9 + t) * Co + co) * 32 + (sl << 3) + (kk & 7)] =
        f2bf(w[co * n + i] * s[ci] * d);
  }
}

// ---------- feat: conv1x1 3->32 + relu + bn @128^2 -> NHWC bf16 + fp32 rgb planes -----
__global__ void __launch_bounds__(256) feat_kernel(
    const float* __restrict__ rgbs, const float* __restrict__ cw, const float* __restrict__ cb,
    const float* __restrict__ gam, const float* __restrict__ bet,
    const float* __restrict__ mean, const float* __restrict__ var,
    unsigned short* __restrict__ feat, float* __restrict__ rgbf)
{
  const int p = blockIdx.x * 256 + threadIdx.x;
  const float r = rgbs[p], g = rgbs[16384 + p], b = rgbs[32768 + p];
  unsigned int pk[16];
#pragma unroll
  for (int co = 0; co < 32; ++co) {
    float v = cw[co * 3] * r + cw[co * 3 + 1] * g + cw[co * 3 + 2] * b + cb[co];
    v = fmaxf(v, 0.f);
    float inv = rsqrtf(var[co] + 1e-5f);
    v = (v - mean[co]) * (inv * gam[co]) + bet[co];
    if (co < 3) rgbf[co * 16384 + p] = v;
    unsigned int h = f2bf(v);
    if ((co & 1) == 0) pk[co >> 1] = h;
    else               pk[co >> 1] |= h << 16;
  }
  uint4* dst = reinterpret_cast<uint4*>(feat + (size_t)p * 32);
#pragma unroll
  for (int q = 0; q < 4; ++q)
    dst[q] = make_uint4(pk[q * 4], pk[q * 4 + 1], pk[q * 4 + 2], pk[q * 4 + 3]);
}

// ---------------- NHWC bf16 2x antialiased upsample ----------------
__global__ void __launch_bounds__(256) up2x_nhwc_kernel(
    const unsigned short* __restrict__ in, unsigned short* __restrict__ out,
    int H, int W, int c8s /*log2(C/8)*/, int w2s /*log2(2W)*/)
{
  const int cid = blockIdx.x * 256 + threadIdx.x;
  const int k = cid & ((1 << c8s) - 1);
  const int pix = cid >> c8s;
  const int ey = pix >> w2s;
  const int ex = pix & ((1 << w2s) - 1);
  const int C = 8 << c8s;
  int ry0; float ay0, ay1;
  if (ey & 1) { ry0 = ey >> 1;       ay0 = 0.75f; ay1 = 0.25f; }
  else        { ry0 = (ey >> 1) - 1; ay0 = 0.25f; ay1 = 0.75f; }
  int cx0; float bx0, bx1;
  if (ex & 1) { cx0 = ex >> 1;       bx0 = 0.75f; bx1 = 0.25f; }
  else        { cx0 = (ex >> 1) - 1; bx0 = 0.25f; bx1 = 0.75f; }
  const short8 z = {0, 0, 0, 0, 0, 0, 0, 0};
  short8 v00 = z, v01 = z, v10 = z, v11 = z;
  const bool yo0 = (ry0 >= 0), yo1 = (ry0 + 1 < H);
  const bool xo0 = (cx0 >= 0), xo1 = (cx0 + 1 < W);
  if (yo0 && xo0) v00 = *reinterpret_cast<const short8*>(in + ((size_t)(ry0 * W + cx0) * C + k * 8));
  if (yo0 && xo1) v01 = *reinterpret_cast<const short8*>(in + ((size_t)(ry0 * W + cx0 + 1) * C + k * 8));
  if (yo1 && xo0) v10 = *reinterpret_cast<const short8*>(in + ((size_t)((ry0 + 1) * W + cx0) * C + k * 8));
  if (yo1 && xo1) v11 = *reinterpret_cast<const short8*>(in + ((size_t)((ry0 + 1) * W + cx0 + 1) * C + k * 8));
  unsigned int o[4];
#pragma unroll
  for (int j = 0; j < 8; ++j) {
    float f = ay0 * (bx0 * b2f(v00[j]) + bx1 * b2f(v01[j]))
            + ay1 * (bx0 * b2f(v10[j]) + bx1 * b2f(v11[j]));
    unsigned int h = f2bf(f);
    if ((j & 1) == 0) o[j >> 1] = h;
    else              o[j >> 1] |= h << 16;
  }
  *reinterpret_cast<uint4*>(out + (size_t)pix * C + k * 8) = make_uint4(o[0], o[1], o[2], o[3]);
}

// ---------------- conv3x3 via MFMA implicit GEMM (NHWC bf16) ----------------
// Block: 8 waves (512 thr), 32x16 pixel tile, 128-co slice (cogB = blockIdx.y*128).
// Wave (wr=wv&3, wg=wv>>2): rows wr*8..wr*8+7 x 16 cols x 64 co (wg selects group).
// 288 MFMA / wave / chunk; A-frags reused 8x, B via 10-row rolling register window
// (30 ds_read/chunk) -> 235 B LDS per MFMA (was 384; LDS BW was the binding limit).
// Weights LDS-staged per 3-tap kx group (2-deep ring); acts dbuf. 3 barriers/chunk.
template <bool FUSE_RGB>
__global__ void __launch_bounds__(512) conv3x3_mfma(
    const unsigned short* __restrict__ in,   // [H][W][Ci] bf16
    const unsigned short* __restrict__ wq,   // [Ci/32][9][Co][32] bf16 (slot-swizzled)
    const float* __restrict__ bias,          // [Co]
    unsigned short* __restrict__ out,        // [H][W][Co] bf16 (or null)
    const float* __restrict__ rgbw,          // [3][Co] fp32 (FUSE)
    float* __restrict__ rgbp,                // [2][3][H*W] fp32 (FUSE)
    const unsigned short* __restrict__ zpage,// >=512B of zeros
    int H, int W, int Ci, int Co)
{
  const int tid  = threadIdx.x;
  const int lane = tid & 63;
  const int wv   = tid >> 6;          // 0..7
  const int wr   = wv & 3;            // row group (8 rows each)
  const int wg   = wv >> 2;           // co-group within block (0/1)
  const int lo   = lane & 15, hi = lane >> 4;
  const int tpr  = W >> 4;
  const int T_y  = (blockIdx.x / tpr) << 5;   // 32-row tile
  const int T_x  = (blockIdx.x % tpr) << 4;
  const int cogB = blockIdx.y << 7;   // block's 128-co weight slice
  const int cog  = cogB + (wg << 6);

  __shared__ short8 xs[2][2448];      // act dbuf [pix 34*18][4 k-slots]
  __shared__ short8 wlds[2][1536];    // weight ring [buf][ky 3][co 128][slot 4]
  __shared__ float  rw[FUSE_RGB ? 384 : 4];

  if (FUSE_RGB) {
    for (int i = tid; i < 3 * Co; i += 512) rw[i] = rgbw[i];
  }

  f32x4 acc[4][8];
#pragma unroll
  for (int a = 0; a < 4; ++a)
#pragma unroll
    for (int b = 0; b < 8; ++b) acc[a][b] = (f32x4){0.f, 0.f, 0.f, 0.f};

  // ---- ci-invariant act staging sources (slot = j*512 + tid, linear; 2448 slots) ----
  const unsigned short* gsrc[5];
#pragma unroll
  for (int j = 0; j < 5; ++j) {
    const int s = j * 512 + tid;
    const int pix = s >> 2, kslot = s & 3;
    const int rr = pix / 18, cc = pix - rr * 18;
    const int gy = T_y - 1 + rr, gx = T_x - 1 + cc;
    const int k = kslot ^ ((cc >> 1) & 3);      // inverse swizzle on the SOURCE
    const bool inb = (s < 2448) && gy >= 0 && gy < H && gx >= 0 && gx < W;
    gsrc[j] = inb ? (in + ((size_t)(gy * W + gx) * Ci + (k << 3))) : zpage;
  }

#define STAGE(c, buf)                                                              \
  {                                                                                \
    const int cb_ = (c) << 5;                                                      \
    _Pragma("unroll")                                                              \
    for (int j = 0; j < 4; ++j)                                                    \
      __builtin_amdgcn_global_load_lds((glob_void*)(gsrc[j] + cb_),                \
                                       (lds_void*)&xs[buf][j * 512 + tid], 16, 0, 0); \
    if (tid < 400)                                                                 \
      __builtin_amdgcn_global_load_lds((glob_void*)(gsrc[4] + cb_),                \
                                       (lds_void*)&xs[buf][2048 + tid], 16, 0, 0); \
  }

  // weight group stage: taps {KX, KX+3, KX+6} of chunk C -> wlds[BUF], linear copy
#define STAGE_W(C, KX, BUF)                                                        \
  {                                                                                \
    _Pragma("unroll")                                                              \
    for (int j = 0; j < 3; ++j) {                                                  \
      const unsigned short* src_ =                                                 \
          wq + ((size_t)((C) * 9 + j * 3 + (KX)) * Co + cogB) * 32 + tid * 8;      \
      __builtin_amdgcn_global_load_lds((glob_void*)src_,                           \
                                       (lds_void*)&wlds[BUF][(j << 9) + tid], 16, 0, 0); \
    }                                                                              \
  }

  // A-fragment read from wlds: co_blk = wg*64+cf*16+lo, slot = hi ^ sxa
  const int sxa   = (lo & 3) ^ ((lo >> 2) & 3);
  const int wbase = (((wg << 6) + lo) << 2) + (hi ^ sxa);
#define ALOADW(SLOT, KY, BUF)                                                      \
  {                                                                                \
    _Pragma("unroll")                                                              \
    for (int cf = 0; cf < 4; ++cf)                                                 \
      apf[SLOT][cf] = wlds[BUF][((KY) << 9) + wbase + (cf << 6)];                  \
  }

#define MF(A, B, C) __builtin_amdgcn_mfma_f32_16x16x32_bf16(A, B, C, 0, 0, 0)

  // prologue: stage act chunk 0 + weight group (c=0, kx=0)
  STAGE(0, 0);
  STAGE_W(0, 0, 0);
  __syncthreads();

  const int nch = Ci >> 5;
  const int rstride = 72;   // 18*4 short8 per tile row
  int wb = 0;
  for (int c = 0; c < nch; ++c) {
    const int cur = c & 1;
#pragma unroll
    for (int g = 0; g < 3; ++g) {            // g = kx
      // issue next weight-group staging (drained at this group's barrier)
      if (g < 2)             { STAGE_W(c, g + 1, wb ^ 1); }
      else if (c + 1 < nch)  { STAGE_W(c + 1, 0, wb ^ 1); }
      if (g == 0 && c + 1 < nch) STAGE(c + 1, cur ^ 1);

      const int tx2  = lo + g;
      const int xv_  = hi ^ ((tx2 >> 1) & 3);
      const int rowb = (((wr << 3) * 18 + tx2) << 2) + xv_;   // row wr*8, col tx2

      short8 q0 = xs[cur][rowb];
      short8 q1 = xs[cur][rowb + rstride];
      short8 q2 = xs[cur][rowb + 2 * rstride];
      short8 q3 = xs[cur][rowb + 3 * rstride];
      short8 q4 = xs[cur][rowb + 4 * rstride];
      short8 q5 = xs[cur][rowb + 5 * rstride];
      short8 q6 = xs[cur][rowb + 6 * rstride];
      short8 q7 = xs[cur][rowb + 7 * rstride];

      short8 apf[2][4];
      ALOADW(0, 0, wb);
      ALOADW(1, 1, wb);
      // ky = 0: rows r+0 -> q0..q7
#pragma unroll
      for (int cf = 0; cf < 4; ++cf) {
        acc[cf][0] = MF(apf[0][cf], q0, acc[cf][0]);
        acc[cf][1] = MF(apf[0][cf], q1, acc[cf][1]);
        acc[cf][2] = MF(apf[0][cf], q2, acc[cf][2]);
        acc[cf][3] = MF(apf[0][cf], q3, acc[cf][3]);
        acc[cf][4] = MF(apf[0][cf], q4, acc[cf][4]);
        acc[cf][5] = MF(apf[0][cf], q5, acc[cf][5]);
        acc[cf][6] = MF(apf[0][cf], q6, acc[cf][6]);
        acc[cf][7] = MF(apf[0][cf], q7, acc[cf][7]);
      }
      // ky = 1: rows r+1 -> q1..q8
      short8 q8 = xs[cur][rowb + 8 * rstride];
      ALOADW(0, 2, wb);
#pragma unroll
      for (int cf = 0; cf < 4; ++cf) {
        acc[cf][0] = MF(apf[1][cf], q1, acc[cf][0]);
        acc[cf][1] = MF(apf[1][cf], q2, acc[cf][1]);
        acc[cf][2] = MF(apf[1][cf], q3, acc[cf][2]);
        acc[cf][3] = MF(apf[1][cf], q4, acc[cf][3]);
        acc[cf][4] = MF(apf[1][cf], q5, acc[cf][4]);
        acc[cf][5] = MF(apf[1][cf], q6, acc[cf][5]);
        acc[cf][6] = MF(apf[1][cf], q7, acc[cf][6]);
        acc[cf][7] = MF(apf[1][cf], q8, acc[cf][7]);
      }
      // ky = 2: rows r+2 -> q2..q9
      short8 q9 = xs[cur][rowb + 9 * rstride];
#pragma unroll
      for (int cf = 0; cf < 4; ++cf) {
        acc[cf][0] = MF(apf[0][cf], q2, acc[cf][0]);
        acc[cf][1] = MF(apf[0][cf], q3, acc[cf][1]);
        acc[cf][2] = MF(apf[0][cf], q4, acc[cf][2]);
        acc[cf][3] = MF(apf[0][cf], q5, acc[cf][3]);
        acc[cf][4] = MF(apf[0][cf], q6, acc[cf][4]);
        acc[cf][5] = MF(apf[0][cf], q7, acc[cf][5]);
        acc[cf][6] = MF(apf[0][cf], q8, acc[cf][6]);
        acc[cf][7] = MF(apf[0][cf], q9, acc[cf][7]);
      }
      __syncthreads();     // publishes wlds[wb^1] (+ act at g==0); readers of wb done
      wb ^= 1;
    }
  }
#undef STAGE
#undef STAGE_W
#undef ALOADW
#undef MF

  // ---- epilogue ----
  const float rt2 = 1.41421356237309515f;
#pragma unroll
  for (int r = 0; r < 8; ++r) {
    const int gy = T_y + (wr << 3) + r;
    const int gx = T_x + lo;
    if (!FUSE_RGB) {
#pragma unroll
      for (int cf = 0; cf < 4; ++cf) {
        const int cb = cog + (cf << 4) + (hi << 2);
        const f32x4 bi = *reinterpret_cast<const f32x4*>(bias + cb);
        unsigned short h[4];
#pragma unroll
        for (int reg = 0; reg < 4; ++reg) {
          float vv = acc[cf][r][reg] + bi[reg];
          vv = (vv >= 0.f) ? vv : 0.2f * vv;
          vv *= rt2;
          vv = fminf(fmaxf(vv, -256.f), 256.f);
          h[reg] = f2bf(vv);
        }
        uint2 pk;
        pk.x = (unsigned int)h[0] | ((unsigned int)h[1] << 16);
        pk.y = (unsigned int)h[2] | ((unsigned int)h[3] << 16);
        *reinterpret_cast<uint2*>(out + (size_t)(gy * W + gx) * Co + cb) = pk;
      }
    } else {
      float p0 = 0.f, p1 = 0.f, p2 = 0.f;
#pragma unroll
      for (int cf = 0; cf < 4; ++cf) {
        const int cb = cog + (cf << 4) + (hi << 2);
        const f32x4 bi = *reinterpret_cast<const f32x4*>(bias + cb);
#pragma unroll
        for (int reg = 0; reg < 4; ++reg) {
          float vv = acc[cf][r][reg] + bi[reg];
          vv = (vv >= 0.f) ? vv : 0.2f * vv;
          vv *= rt2;
          vv = fminf(fmaxf(vv, -256.f), 256.f);
          p0 = fmaf(rw[cb + reg], vv, p0);
          p1 = fmaf(rw[Co + cb + reg], vv, p1);
          p2 = fmaf(rw[2 * Co + cb + reg], vv, p2);
        }
      }
      p0 += __shfl_xor(p0, 16); p0 += __shfl_xor(p0, 32);
      p1 += __shfl_xor(p1, 16); p1 += __shfl_xor(p1, 32);
      p2 += __shfl_xor(p2, 16); p2 += __shfl_xor(p2, 32);
      if (hi == 0) {
        const size_t HWs = (size_t)H * W;
        const size_t px  = (size_t)gy * W + gx;
        rgbp[((size_t)wg * 3 + 0) * HWs + px] = p0;
        rgbp[((size_t)wg * 3 + 1) * HWs + px] = p1;
        rgbp[((size_t)wg * 3 + 2) * HWs + px] = p2;
      }
    }
  }
}

// ---------------- fp32-plane upfirdn2d sampler ----------------
__device__ __forceinline__ float up2x_sample(const float* __restrict__ im, int H, int W,
                                             int oy, int ox)
{
  int my = oy >> 1, mx = ox >> 1;
  int ry0; float ay0, ay1;
  if (oy & 1) { ry0 = my;     ay0 = 0.75f; ay1 = 0.25f; }
  else        { ry0 = my - 1; ay0 = 0.25f; ay1 = 0.75f; }
  int cx0; float bx0, bx1;
  if (ox & 1) { cx0 = mx;     bx0 = 0.75f; bx1 = 0.25f; }
  else        { cx0 = mx - 1; bx0 = 0.25f; bx1 = 0.75f; }
  float v00 = (ry0 >= 0    && cx0 >= 0   ) ? im[ry0 * W + cx0]           : 0.f;
  float v01 = (ry0 >= 0    && cx0 + 1 < W) ? im[ry0 * W + cx0 + 1]       : 0.f;
  float v10 = (ry0 + 1 < H && cx0 >= 0   ) ? im[(ry0 + 1) * W + cx0]     : 0.f;
  float v11 = (ry0 + 1 < H && cx0 + 1 < W) ? im[(ry0 + 1) * W + cx0 + 1] : 0.f;
  return ay0 * (bx0 * v00 + bx1 * v01) + ay1 * (bx0 * v10 + bx1 * v11);
}

// ---------------- img0 = up2x(rgb_fp32) + clip(to_rgb0(x1)) @256^2 ----------------
__global__ void __launch_bounds__(256) img0_kernel(
    const float* __restrict__ rgbf, const unsigned short* __restrict__ x1,
    const float* __restrict__ mt0g, const float* __restrict__ tb,
    float* __restrict__ img0)
{
  __shared__ float mt[768];
  const int tid = threadIdx.x;
  for (int i = tid; i < 768; i += 256) mt[i] = mt0g[i];
  __syncthreads();
  const int p = blockIdx.x * 256 + tid;
  const unsigned short* xp = x1 + (size_t)p * 256;
  float a0 = 0.f, a1 = 0.f, a2 = 0.f;
  for (int i8 = 0; i8 < 32; ++i8) {
    const short8 v = *reinterpret_cast<const short8*>(xp + i8 * 8);
#pragma unroll
    for (int j = 0; j < 8; ++j) {
      const float xv = b2f(v[j]);
      const int ci = i8 * 8 + j;
      a0 = fmaf(mt[ci],       xv, a0);
      a1 = fmaf(mt[256 + ci], xv, a1);
      a2 = fmaf(mt[512 + ci], xv, a2);
    }
  }
  const int oy = p >> 8, ox = p & 255;
  float av[3] = {a0, a1, a2};
#pragma unroll
  for (int o = 0; o < 3; ++o) {
    float y = fminf(fmaxf(av[o] + tb[o], -256.f), 256.f);
    img0[o * 65536 + p] = up2x_sample(rgbf + o * 16384, 128, 128, oy, ox) + y;
  }
}

// ---------------- out = up2x(img0) + clip(sum rgbp + tb) @512^2 ----------------
__global__ void __launch_bounds__(256) final_kernel(
    const float* __restrict__ img0, const float* __restrict__ rgbp,
    const float* __restrict__ tb, float* __restrict__ out)
{
  const int p = blockIdx.x * 256 + threadIdx.x;
  const int oy = p >> 9, ox = p & 511;
#pragma unroll
  for (int o = 0; o < 3; ++o) {
    float a = rgbp[(0 * 3 + o) * 262144 + p] + rgbp[(1 * 3 + o) * 262144 + p];
    float y = fminf(fmaxf(a + tb[o], -256.f), 256.f);
    out[o * 262144 + p] = up2x_sample(img0 + o * 65536, 256, 256, oy, ox) + y;
  }
}

// ---------------- launch ----------------
extern "C" void kernel_launch(void* const* d_in, const int* in_sizes, int n_in,
                              void* d_out, int out_size, void* d_ws, size_t ws_size,
                              hipStream_t stream)
{
  const float* rays   = (const float*)d_in[0];
  const float* rgbs   = (const float*)d_in[1];
  const float* conv_w = (const float*)d_in[2];
  const float* conv_b = (const float*)d_in[3];
  const float* bn_g   = (const float*)d_in[4];
  const float* bn_b   = (const float*)d_in[5];
  const float* bn_m   = (const float*)d_in[6];
  const float* bn_v   = (const float*)d_in[7];
  const float* a0_w   = (const float*)d_in[8];
  const float* a0_b   = (const float*)d_in[9];
  const float* w0     = (const float*)d_in[10];
  const float* b0     = (const float*)d_in[11];
  const float* a1_w   = (const float*)d_in[12];
  const float* a1_b   = (const float*)d_in[13];
  const float* w1     = (const float*)d_in[14];
  const float* b1     = (const float*)d_in[15];
  const float* t0_aw  = (const float*)d_in[16];
  const float* t0_ab  = (const float*)d_in[17];
  const float* t0_w   = (const float*)d_in[18];
  const float* t0_b   = (const float*)d_in[19];
  const float* a2_w   = (const float*)d_in[20];
  const float* a2_b   = (const float*)d_in[21];
  const float* w2     = (const float*)d_in[22];
  const float* b2     = (const float*)d_in[23];
  const float* a3_w   = (const float*)d_in[24];
  const float* a3_b   = (const float*)d_in[25];
  const float* w3     = (const float*)d_in[26];
  const float* b3     = (const float*)d_in[27];
  const float* t1_aw  = (const float*)d_in[28];
  const float* t1_ab  = (const float*)d_in[29];
  const float* t1_w   = (const float*)d_in[30];
  const float* t1_b   = (const float*)d_in[31];

  float* ws  = (float*)d_ws;
  float* out = (float*)d_out;

  unsigned short* wq0   = (unsigned short*)(ws + OFF_WQ0);
  unsigned short* wq1   = (unsigned short*)(ws + OFF_WQ1);
  unsigned short* wq2   = (unsigned short*)(ws + OFF_WQ2);
  unsigned short* wq3   = (unsigned short*)(ws + OFF_WQ3);
  unsigned short* featb = (unsigned short*)(ws + OFF_FEAT);
  unsigned short* ufeat = (unsigned short*)(ws + OFF_UFEAT);
  unsigned short* x0b   = (unsigned short*)(ws + OFF_X0);
  unsigned short* x1b   = (unsigned short*)(ws + OFF_X1);
  unsigned short* x2b   = (unsigned short*)(ws + OFF_X2);
  unsigned short* Ub    = (unsigned short*)(ws + OFF_U);
  const unsigned short* zpage = (const unsigned short*)(ws + OFF_ZERO);

  prep_kernel<<<1, 256, 0, stream>>>(rays, a0_w, a0_b, a1_w, a1_b, t0_aw, t0_ab,
                                     a2_w, a2_b, a3_w, a3_b, t1_aw, t1_ab,
                                     t0_w, t1_w, ws);
  modw_kernel<<<256, 256, 0, stream>>>(w0, ws + OFF_S0, wq0, 32, 256);
  modw_kernel<<<256, 256, 0, stream>>>(w1, ws + OFF_S1, wq1, 256, 256);
  modw_kernel<<<128, 256, 0, stream>>>(w2, ws + OFF_S2, wq2, 256, 128);
  modw_kernel<<<128, 256, 0, stream>>>(w3, ws + OFF_S3, wq3, 128, 128);
  feat_kernel<<<64, 256, 0, stream>>>(rgbs, conv_w, conv_b, bn_g, bn_b, bn_m, bn_v,
                                      featb, ws + OFF_RGBF);
  // up(feat) -> ufeat  (128->256, C=32: c8s=2, w2s=8)
  up2x_nhwc_kernel<<<1024, 256, 0, stream>>>(featb, ufeat, 128, 128, 2, 8);
  // L0: ufeat(32) -> x0(256) @256^2   (tiles 32x16 -> 8*16=128 blocks; 2 co-slices)
  conv3x3_mfma<false><<<dim3(128, 2), 512, 0, stream>>>(
      ufeat, wq0, b0, x0b, nullptr, nullptr, zpage, 256, 256, 32, 256);
  // L1: x0(256) -> x1(256) @256^2
  conv3x3_mfma<false><<<dim3(128, 2), 512, 0, stream>>>(
      x0b, wq1, b1, x1b, nullptr, nullptr, zpage, 256, 256, 256, 256);
  // img0 = up2x(rgb) + to_rgb0(x1)
  img0_kernel<<<256, 256, 0, stream>>>(ws + OFF_RGBF, x1b, ws + OFF_MT0, t0_b,
                                       ws + OFF_IMG0);
  // up(x1) -> U  (256->512, C=256: c8s=5, w2s=9)
  up2x_nhwc_kernel<<<32768, 256, 0, stream>>>(x1b, Ub, 256, 256, 5, 9);
  // L2: U(256) -> x2(128) @512^2  (tiles 16*32=512 blocks, single 128-co slice)
  conv3x3_mfma<false><<<dim3(512, 1), 512, 0, stream>>>(
      Ub, wq2, b2, x2b, nullptr, nullptr, zpage, 512, 512, 256, 128);
  // L3: x2(128) -> fused to_rgb1 partials @512^2
  conv3x3_mfma<true><<<dim3(512, 1), 512, 0, stream>>>(
      x2b, wq3, b3, nullptr, ws + OFF_MT1, ws + OFF_RGBP, zpage, 512, 512, 128, 128);
  // out = up2x(img0) + clip(rgbp sum + t1_b)
  final_kernel<<<1024, 256, 0, stream>>>(ws + OFF_IMG0, ws + OFF_RGBP, t1_b, out);
}

// Round 15
// 404.669 us; speedup vs baseline: 2.4111x; 1.0120x over previous
//
#include <hip/hip_runtime.h>
#include <cstddef>

typedef __attribute__((ext_vector_type(8))) short short8;
typedef __attribute__((ext_vector_type(4))) float f32x4;
typedef __attribute__((address_space(3))) void lds_void;
typedef const __attribute__((address_space(1))) void glob_void;

// ---------------- workspace layout (float offsets), total 54525952 f = 208 MiB ------
static const size_t OFF_S0    = 0;         // 32
static const size_t OFF_S1    = 64;        // 256
static const size_t OFF_S2    = 320;       // 256
static const size_t OFF_S3    = 576;       // 128
static const size_t OFF_MT0   = 704;       // 768  fp32 [3][256]
static const size_t OFF_MT1   = 1472;      // 384  fp32 [3][128]
static const size_t OFF_ZERO  = 1856;      // 128 fp32 zeros page (OOB gload_lds target)
static const size_t OFF_RGBF  = 2048;      // 3*128*128 fp32 (skip-path rgb, full precision)
static const size_t OFF_IMG0  = 51200;     // 3*256*256 fp32
static const size_t OFF_RGBP  = 247808;    // 2*3*512*512 fp32 (layer3 fused to_rgb partials)
static const size_t OFF_WQ0   = 1900544;   // bf16 [1][9][256][32]  (slot-swizzled)
static const size_t OFF_WQ1   = 1937408;   // bf16 [8][9][256][32]
static const size_t OFF_WQ2   = 2232320;   // bf16 [8][9][128][32]
static const size_t OFF_WQ3   = 2379776;   // bf16 [4][9][128][32]
static const size_t OFF_FEAT  = 2453504;   // bf16 NHWC [128][128][32]
static const size_t OFF_UFEAT = 2715648;   // bf16 NHWC [256][256][32]
static const size_t OFF_X1    = 4194304;   // bf16 NHWC [256][256][256] (inside X2 region)
static const size_t OFF_X2    = 4194304;   // bf16 NHWC [512][512][128] (overwrites dead x1)
static const size_t OFF_U     = 20971520;  // bf16 NHWC [512][512][256] = 33554432 f
static const size_t OFF_X0    = 20971520;  // bf16 NHWC [256][256][256] (dead before U written)
// timeline: feat->ufeat->L0(x0@U)->L1(x0->x1)->img0(x1)->up(x1->U)->L2(U->x2)->L3(x2->rgbp)->final

__device__ __forceinline__ unsigned short f2bf(float f) {
  unsigned int u = __float_as_uint(f);
  return (unsigned short)((u + 0x7FFFu + ((u >> 16) & 1u)) >> 16);
}
__device__ __forceinline__ float b2f(short h) {
  return __uint_as_float(((unsigned int)(unsigned short)h) << 16);
}

// ---------------- prep: w_vec, styles, to_rgb modulated weights (fp32) ----------------
__global__ void __launch_bounds__(256) prep_kernel(
    const float* __restrict__ rays,
    const float* __restrict__ a0w, const float* __restrict__ a0b,
    const float* __restrict__ a1w, const float* __restrict__ a1b,
    const float* __restrict__ t0aw, const float* __restrict__ t0ab,
    const float* __restrict__ a2w, const float* __restrict__ a2b,
    const float* __restrict__ a3w, const float* __restrict__ a3b,
    const float* __restrict__ t1aw, const float* __restrict__ t1ab,
    const float* __restrict__ t0w, const float* __restrict__ t1w,
    float* __restrict__ ws)
{
  __shared__ float wv[72];
  __shared__ float st0l[256];
  __shared__ float st1l[128];
  const int tid = threadIdx.x;
  if (tid < 128) ws[OFF_ZERO + tid] = 0.f;   // zeros page for OOB gload_lds
  if (tid < 36) {
    int i = tid / 12, j = tid % 12;
    float v = rays[i * 16384] * (float)(1 << j);
    wv[tid]      = sinf(v);
    wv[36 + tid] = cosf(v);
  }
  __syncthreads();
  const float inv72 = 0.11785113019775793f;   // 1/sqrt(72)

  if (tid < 32) {
    float d = 0.f;
    for (int k = 0; k < 72; ++k) d += wv[k] * a0w[tid * 72 + k];
    ws[OFF_S0 + tid] = fmaf(d, inv72, a0b[tid]);
  }
  {
    float d = 0.f;
    for (int k = 0; k < 72; ++k) d += wv[k] * a1w[tid * 72 + k];
    ws[OFF_S1 + tid] = fmaf(d, inv72, a1b[tid]);
  }
  {
    float d = 0.f;
    for (int k = 0; k < 72; ++k) d += wv[k] * t0aw[tid * 72 + k];
    st0l[tid] = fmaf(d, inv72, t0ab[tid]) * 0.0625f;       // /sqrt(256)
  }
  {
    float d = 0.f;
    for (int k = 0; k < 72; ++k) d += wv[k] * a2w[tid * 72 + k];
    ws[OFF_S2 + tid] = fmaf(d, inv72, a2b[tid]);
  }
  if (tid < 128) {
    float d = 0.f;
    for (int k = 0; k < 72; ++k) d += wv[k] * a3w[tid * 72 + k];
    ws[OFF_S3 + tid] = fmaf(d, inv72, a3b[tid]);
  }
  if (tid < 128) {
    float d = 0.f;
    for (int k = 0; k < 72; ++k) d += wv[k] * t1aw[tid * 72 + k];
    st1l[tid] = fmaf(d, inv72, t1ab[tid]) * 0.08838834764831845f;  // /sqrt(128)
  }
  __syncthreads();
  for (int i = tid; i < 768; i += 256) ws[OFF_MT0 + i] = t0w[i] * st0l[i & 255];
  for (int i = tid; i < 384; i += 256) ws[OFF_MT1 + i] = t1w[i] * st1l[i & 127];
}

// ------ weight modulate + demodulate -> bf16 [ci/32][tap][Co][slot-swizzled 32] ------
__global__ void __launch_bounds__(256) modw_kernel(
    const float* __restrict__ w, const float* __restrict__ s,
    unsigned short* __restrict__ wq, int Ci, int Co)
{
  const int co = blockIdx.x;
  const int n = Ci * 9;
  float local = 0.f;
  for (int i = threadIdx.x; i < n; i += 256) {
    float v = w[co * n + i] * s[i / 9];
    local += v * v;
  }
#pragma unroll
  for (int off = 32; off >= 1; off >>= 1) local += __shfl_xor(local, off);
  __shared__ float red[4];
  if ((threadIdx.x & 63) == 0) red[threadIdx.x >> 6] = local;
  __syncthreads();
  const float d = rsqrtf(red[0] + red[1] + red[2] + red[3] + 1e-8f);
  const int sxor = (co & 3) ^ ((co >> 2) & 3);
  for (int i = threadIdx.x; i < n; i += 256) {
    int ci = i / 9, t = i - ci * 9;
    int kk = ci & 31;
    int sl = (kk >> 3) ^ sxor;
    wq[(((size_t)(ci >> 5) * 9 + t) * Co + co) * 32 + (sl << 3) + (kk & 7)] =
        f2bf(w[co * n + i] * s[ci] * d);
  }
}

// ---------- feat: conv1x1 3->32 + relu + bn @128^2 -> NHWC bf16 + fp32 rgb planes -----
__global__ void __launch_bounds__(256) feat_kernel(
    const float* __restrict__ rgbs, const float* __restrict__ cw, const float* __restrict__ cb,
    const float* __restrict__ gam, const float* __restrict__ bet,
    const float* __restrict__ mean, const float* __restrict__ var,
    unsigned short* __restrict__ feat, float* __restrict__ rgbf)
{
  const int p = blockIdx.x * 256 + threadIdx.x;
  const float r = rgbs[p], g = rgbs[16384 + p], b = rgbs[32768 + p];
  unsigned int pk[16];
#pragma unroll
  for (int co = 0; co < 32; ++co) {
    float v = cw[co * 3] * r + cw[co * 3 + 1] * g + cw[co * 3 + 2] * b + cb[co];
    v = fmaxf(v, 0.f);
    float inv = rsqrtf(var[co] + 1e-5f);
    v = (v - mean[co]) * (inv * gam[co]) + bet[co];
    if (co < 3) rgbf[co * 16384 + p] = v;
    unsigned int h = f2bf(v);
    if ((co & 1) == 0) pk[co >> 1] = h;
    else               pk[co >> 1] |= h << 16;
  }
  uint4* dst = reinterpret_cast<uint4*>(feat + (size_t)p * 32);
#pragma unroll
  for (int q = 0; q < 4; ++q)
    dst[q] = make_uint4(pk[q * 4], pk[q * 4 + 1], pk[q * 4 + 2], pk[q * 4 + 3]);
}

// ---------------- NHWC bf16 2x antialiased upsample ----------------
__global__ void __launch_bounds__(256) up2x_nhwc_kernel(
    const unsigned short* __restrict__ in, unsigned short* __restrict__ out,
    int H, int W, int c8s /*log2(C/8)*/, int w2s /*log2(2W)*/)
{
  const int cid = blockIdx.x * 256 + threadIdx.x;
  const int k = cid & ((1 << c8s) - 1);
  const int pix = cid >> c8s;
  const int ey = pix >> w2s;
  const int ex = pix & ((1 << w2s) - 1);
  const int C = 8 << c8s;
  int ry0; float ay0, ay1;
  if (ey & 1) { ry0 = ey >> 1;       ay0 = 0.75f; ay1 = 0.25f; }
  else        { ry0 = (ey >> 1) - 1; ay0 = 0.25f; ay1 = 0.75f; }
  int cx0; float bx0, bx1;
  if (ex & 1) { cx0 = ex >> 1;       bx0 = 0.75f; bx1 = 0.25f; }
  else        { cx0 = (ex >> 1) - 1; bx0 = 0.25f; bx1 = 0.75f; }
  const short8 z = {0, 0, 0, 0, 0, 0, 0, 0};
  short8 v00 = z, v01 = z, v10 = z, v11 = z;
  const bool yo0 = (ry0 >= 0), yo1 = (ry0 + 1 < H);
  const bool xo0 = (cx0 >= 0), xo1 = (cx0 + 1 < W);
  if (yo0 && xo0) v00 = *reinterpret_cast<const short8*>(in + ((size_t)(ry0 * W + cx0) * C + k * 8));
  if (yo0 && xo1) v01 = *reinterpret_cast<const short8*>(in + ((size_t)(ry0 * W + cx0 + 1) * C + k * 8));
  if (yo1 && xo0) v10 = *reinterpret_cast<const short8*>(in + ((size_t)((ry0 + 1) * W + cx0) * C + k * 8));
  if (yo1 && xo1) v11 = *reinterpret_cast<const short8*>(in + ((size_t)((ry0 + 1) * W + cx0 + 1) * C + k * 8));
  unsigned int o[4];
#pragma unroll
  for (int j = 0; j < 8; ++j) {
    float f = ay0 * (bx0 * b2f(v00[j]) + bx1 * b2f(v01[j]))
            + ay1 * (bx0 * b2f(v10[j]) + bx1 * b2f(v11[j]));
    unsigned int h = f2bf(f);
    if ((j & 1) == 0) o[j >> 1] = h;
    else              o[j >> 1] |= h << 16;
  }
  *reinterpret_cast<uint4*>(out + (size_t)pix * C + k * 8) = make_uint4(o[0], o[1], o[2], o[3]);
}

// ---------------- conv3x3 via MFMA implicit GEMM (NHWC bf16) ----------------
// r12 structure (32x16 tile, 128-co slice, 8-row waves, kx-major rolling B window,
// LDS-staged weights) + counted-vmcnt barriers (T4) + setprio (T5):
//   wlds[3]: buffer g holds taps {g,g+3,g+6}. Per chunk:
//   g0-top: issue W1(3), W2(3), acts_next(5)  -> end-g0: vmcnt(8)+barrier
//   g1:    (no issue)                         -> end-g1: vmcnt(5)+barrier
//   g2-top: issue W0'(3)                      -> end-g2: vmcnt(0)+barrier
// All issue counts wave-uniform (act stage = 5 unconditional loads, xs padded).
template <bool FUSE_RGB>
__global__ void __launch_bounds__(512) conv3x3_mfma(
    const unsigned short* __restrict__ in,   // [H][W][Ci] bf16
    const unsigned short* __restrict__ wq,   // [Ci/32][9][Co][32] bf16 (slot-swizzled)
    const float* __restrict__ bias,          // [Co]
    unsigned short* __restrict__ out,        // [H][W][Co] bf16 (or null)
    const float* __restrict__ rgbw,          // [3][Co] fp32 (FUSE)
    float* __restrict__ rgbp,                // [2][3][H*W] fp32 (FUSE)
    const unsigned short* __restrict__ zpage,// >=512B of zeros
    int H, int W, int Ci, int Co)
{
  const int tid  = threadIdx.x;
  const int lane = tid & 63;
  const int wv   = tid >> 6;          // 0..7
  const int wr   = wv & 3;            // row group (8 rows each)
  const int wg   = wv >> 2;           // co-group within block (0/1)
  const int lo   = lane & 15, hi = lane >> 4;
  const int tpr  = W >> 4;
  const int T_y  = (blockIdx.x / tpr) << 5;   // 32-row tile
  const int T_x  = (blockIdx.x % tpr) << 4;
  const int cogB = blockIdx.y << 7;   // block's 128-co weight slice
  const int cog  = cogB + (wg << 6);

  __shared__ short8 xs[2][2560];      // act dbuf [pix 34*18][4 k-slots] + pad (uniform 5-load stage)
  __shared__ short8 wlds[3][1536];    // weight buffers: [g][ky 3][co 128][slot 4]
  __shared__ float  rw[FUSE_RGB ? 384 : 4];

  if (FUSE_RGB) {
    for (int i = tid; i < 3 * Co; i += 512) rw[i] = rgbw[i];
  }

  f32x4 acc[4][8];
#pragma unroll
  for (int a = 0; a < 4; ++a)
#pragma unroll
    for (int b = 0; b < 8; ++b) acc[a][b] = (f32x4){0.f, 0.f, 0.f, 0.f};

  // ---- ci-invariant act staging sources (slot = j*512 + tid, linear; 2448 live) ----
  const unsigned short* gsrc[5];
#pragma unroll
  for (int j = 0; j < 5; ++j) {
    const int s = j * 512 + tid;
    const int pix = s >> 2, kslot = s & 3;
    const int rr = pix / 18, cc = pix - rr * 18;
    const int gy = T_y - 1 + rr, gx = T_x - 1 + cc;
    const int k = kslot ^ ((cc >> 1) & 3);      // inverse swizzle on the SOURCE
    const bool inb = (s < 2448) && gy >= 0 && gy < H && gx >= 0 && gx < W;
    gsrc[j] = inb ? (in + ((size_t)(gy * W + gx) * Ci + (k << 3))) : zpage;
  }

  // 5 unconditional loads -> wave-uniform vmcnt counts (slots >=2448 land in pad)
#define STAGE(c, buf)                                                              \
  {                                                                                \
    const int cb_ = (c) << 5;                                                      \
    _Pragma("unroll")                                                              \
    for (int j = 0; j < 5; ++j)                                                    \
      __builtin_amdgcn_global_load_lds((glob_void*)(gsrc[j] + cb_),                \
                                       (lds_void*)&xs[buf][j * 512 + tid], 16, 0, 0); \
  }

  // weight group stage: taps {KX, KX+3, KX+6} of chunk C -> wlds[BUF], 3 loads
#define STAGE_W(C, KX, BUF)                                                        \
  {                                                                                \
    _Pragma("unroll")                                                              \
    for (int j = 0; j < 3; ++j) {                                                  \
      const unsigned short* src_ =                                                 \
          wq + ((size_t)((C) * 9 + j * 3 + (KX)) * Co + cogB) * 32 + tid * 8;      \
      __builtin_amdgcn_global_load_lds((glob_void*)src_,                           \
                                       (lds_void*)&wlds[BUF][(j << 9) + tid], 16, 0, 0); \
    }                                                                              \
  }

  const int sxa   = (lo & 3) ^ ((lo >> 2) & 3);
  const int wbase = (((wg << 6) + lo) << 2) + (hi ^ sxa);
#define ALOADW(SLOT, KY, BUF)                                                      \
  {                                                                                \
    _Pragma("unroll")                                                              \
    for (int cf = 0; cf < 4; ++cf)                                                 \
      apf[SLOT][cf] = wlds[BUF][((KY) << 9) + wbase + (cf << 6)];                  \
  }

#define MF(A, B, C) __builtin_amdgcn_mfma_f32_16x16x32_bf16(A, B, C, 0, 0, 0)

  // one kx group: 10-row rolling B window + 3 ky sub-blocks of 32 MFMA each
#define COMPUTE_GROUP(G)                                                           \
  {                                                                                \
    const int tx2  = lo + (G);                                                     \
    const int xv_  = hi ^ ((tx2 >> 1) & 3);                                        \
    const int rowb = (((wr << 3) * 18 + tx2) << 2) + xv_;                          \
    short8 q0 = xs[cur][rowb];                                                     \
    short8 q1 = xs[cur][rowb + 72];                                                \
    short8 q2 = xs[cur][rowb + 2 * 72];                                            \
    short8 q3 = xs[cur][rowb + 3 * 72];                                            \
    short8 q4 = xs[cur][rowb + 4 * 72];                                            \
    short8 q5 = xs[cur][rowb + 5 * 72];                                            \
    short8 q6 = xs[cur][rowb + 6 * 72];                                            \
    short8 q7 = xs[cur][rowb + 7 * 72];                                            \
    short8 apf[2][4];                                                              \
    ALOADW(0, 0, G);                                                               \
    ALOADW(1, 1, G);                                                               \
    __builtin_amdgcn_s_setprio(1);                                                 \
    _Pragma("unroll")                                                              \
    for (int cf = 0; cf < 4; ++cf) {                                               \
      acc[cf][0] = MF(apf[0][cf], q0, acc[cf][0]);                                 \
      acc[cf][1] = MF(apf[0][cf], q1, acc[cf][1]);                                 \
      acc[cf][2] = MF(apf[0][cf], q2, acc[cf][2]);                                 \
      acc[cf][3] = MF(apf[0][cf], q3, acc[cf][3]);                                 \
      acc[cf][4] = MF(apf[0][cf], q4, acc[cf][4]);                                 \
      acc[cf][5] = MF(apf[0][cf], q5, acc[cf][5]);                                 \
      acc[cf][6] = MF(apf[0][cf], q6, acc[cf][6]);                                 \
      acc[cf][7] = MF(apf[0][cf], q7, acc[cf][7]);                                 \
    }                                                                              \
    __builtin_amdgcn_s_setprio(0);                                                 \
    short8 q8 = xs[cur][rowb + 8 * 72];                                            \
    ALOADW(0, 2, G);                                                               \
    __builtin_amdgcn_s_setprio(1);                                                 \
    _Pragma("unroll")                                                              \
    for (int cf = 0; cf < 4; ++cf) {                                               \
      acc[cf][0] = MF(apf[1][cf], q1, acc[cf][0]);                                 \
      acc[cf][1] = MF(apf[1][cf], q2, acc[cf][1]);                                 \
      acc[cf][2] = MF(apf[1][cf], q3, acc[cf][2]);                                 \
      acc[cf][3] = MF(apf[1][cf], q4, acc[cf][3]);                                 \
      acc[cf][4] = MF(apf[1][cf], q5, acc[cf][4]);                                 \
      acc[cf][5] = MF(apf[1][cf], q6, acc[cf][5]);                                 \
      acc[cf][6] = MF(apf[1][cf], q7, acc[cf][6]);                                 \
      acc[cf][7] = MF(apf[1][cf], q8, acc[cf][7]);                                 \
    }                                                                              \
    __builtin_amdgcn_s_setprio(0);                                                 \
    short8 q9 = xs[cur][rowb + 9 * 72];                                            \
    __builtin_amdgcn_s_setprio(1);                                                 \
    _Pragma("unroll")                                                              \
    for (int cf = 0; cf < 4; ++cf) {                                               \
      acc[cf][0] = MF(apf[0][cf], q2, acc[cf][0]);                                 \
      acc[cf][1] = MF(apf[0][cf], q3, acc[cf][1]);                                 \
      acc[cf][2] = MF(apf[0][cf], q4, acc[cf][2]);                                 \
      acc[cf][3] = MF(apf[0][cf], q5, acc[cf][3]);                                 \
      acc[cf][4] = MF(apf[0][cf], q6, acc[cf][4]);                                 \
      acc[cf][5] = MF(apf[0][cf], q7, acc[cf][5]);                                 \
      acc[cf][6] = MF(apf[0][cf], q8, acc[cf][6]);                                 \
      acc[cf][7] = MF(apf[0][cf], q9, acc[cf][7]);                                 \
    }                                                                              \
    __builtin_amdgcn_s_setprio(0);                                                 \
  }

  // prologue: stage acts chunk 0 + weights group 0; full drain
  STAGE(0, 0);
  STAGE_W(0, 0, 0);
  asm volatile("s_waitcnt vmcnt(0) lgkmcnt(0)" ::: "memory");
  __builtin_amdgcn_s_barrier();

  const int nch = Ci >> 5;
  for (int c = 0; c < nch; ++c) {
    const int cur = c & 1;
    const int cnext = (c + 1 < nch) ? (c + 1) : 0;   // last chunk: redundant, uniform

    // ---- group 0: compute wlds[0]; issue W1, W2, acts(next) ----
    STAGE_W(c, 1, 1);
    STAGE_W(c, 2, 2);
    STAGE(cnext, cur ^ 1);
    COMPUTE_GROUP(0)
    asm volatile("s_waitcnt vmcnt(8)" ::: "memory");   // W1 landed (acts+W2 in flight)
    __builtin_amdgcn_s_barrier();

    // ---- group 1: compute wlds[1] ----
    COMPUTE_GROUP(1)
    asm volatile("s_waitcnt vmcnt(5)" ::: "memory");   // W2 landed (acts in flight)
    __builtin_amdgcn_s_barrier();

    // ---- group 2: compute wlds[2]; issue next chunk's W0 ----
    STAGE_W(cnext, 0, 0);
    COMPUTE_GROUP(2)
    asm volatile("s_waitcnt vmcnt(0)" ::: "memory");   // acts + W0' landed
    __builtin_amdgcn_s_barrier();
  }
#undef STAGE
#undef STAGE_W
#undef ALOADW
#undef MF
#undef COMPUTE_GROUP

  // ---- epilogue ----
  const float rt2 = 1.41421356237309515f;
#pragma unroll
  for (int r = 0; r < 8; ++r) {
    const int gy = T_y + (wr << 3) + r;
    const int gx = T_x + lo;
    if (!FUSE_RGB) {
#pragma unroll
      for (int cf = 0; cf < 4; ++cf) {
        const int cb = cog + (cf << 4) + (hi << 2);
        const f32x4 bi = *reinterpret_cast<const f32x4*>(bias + cb);
        unsigned short h[4];
#pragma unroll
        for (int reg = 0; reg < 4; ++reg) {
          float vv = acc[cf][r][reg] + bi[reg];
          vv = (vv >= 0.f) ? vv : 0.2f * vv;
          vv *= rt2;
          vv = fminf(fmaxf(vv, -256.f), 256.f);
          h[reg] = f2bf(vv);
        }
        uint2 pk;
        pk.x = (unsigned int)h[0] | ((unsigned int)h[1] << 16);
        pk.y = (unsigned int)h[2] | ((unsigned int)h[3] << 16);
        *reinterpret_cast<uint2*>(out + (size_t)(gy * W + gx) * Co + cb) = pk;
      }
    } else {
      float p0 = 0.f, p1 = 0.f, p2 = 0.f;
#pragma unroll
      for (int cf = 0; cf < 4; ++cf) {
        const int cb = cog + (cf << 4) + (hi << 2);
        const f32x4 bi = *reinterpret_cast<const f32x4*>(bias + cb);
#pragma unroll
        for (int reg = 0; reg < 4; ++reg) {
          float vv = acc[cf][r][reg] + bi[reg];
          vv = (vv >= 0.f) ? vv : 0.2f * vv;
          vv *= rt2;
          vv = fminf(fmaxf(vv, -256.f), 256.f);
          p0 = fmaf(rw[cb + reg], vv, p0);
          p1 = fmaf(rw[Co + cb + reg], vv, p1);
          p2 = fmaf(rw[2 * Co + cb + reg], vv, p2);
        }
      }
      p0 += __shfl_xor(p0, 16); p0 += __shfl_xor(p0, 32);
      p1 += __shfl_xor(p1, 16); p1 += __shfl_xor(p1, 32);
      p2 += __shfl_xor(p2, 16); p2 += __shfl_xor(p2, 32);
      if (hi == 0) {
        const size_t HWs = (size_t)H * W;
        const size_t px  = (size_t)gy * W + gx;
        rgbp[((size_t)wg * 3 + 0) * HWs + px] = p0;
        rgbp[((size_t)wg * 3 + 1) * HWs + px] = p1;
        rgbp[((size_t)wg * 3 + 2) * HWs + px] = p2;
      }
    }
  }
}

// ---------------- fp32-plane upfirdn2d sampler ----------------
__device__ __forceinline__ float up2x_sample(const float* __restrict__ im, int H, int W,
                                             int oy, int ox)
{
  int my = oy >> 1, mx = ox >> 1;
  int ry0; float ay0, ay1;
  if (oy & 1) { ry0 = my;     ay0 = 0.75f; ay1 = 0.25f; }
  else        { ry0 = my - 1; ay0 = 0.25f; ay1 = 0.75f; }
  int cx0; float bx0, bx1;
  if (ox & 1) { cx0 = mx;     bx0 = 0.75f; bx1 = 0.25f; }
  else        { cx0 = mx - 1; bx0 = 0.25f; bx1 = 0.75f; }
  float v00 = (ry0 >= 0    && cx0 >= 0   ) ? im[ry0 * W + cx0]           : 0.f;
  float v01 = (ry0 >= 0    && cx0 + 1 < W) ? im[ry0 * W + cx0 + 1]       : 0.f;
  float v10 = (ry0 + 1 < H && cx0 >= 0   ) ? im[(ry0 + 1) * W + cx0]     : 0.f;
  float v11 = (ry0 + 1 < H && cx0 + 1 < W) ? im[(ry0 + 1) * W + cx0 + 1] : 0.f;
  return ay0 * (bx0 * v00 + bx1 * v01) + ay1 * (bx0 * v10 + bx1 * v11);
}

// ---------------- img0 = up2x(rgb_fp32) + clip(to_rgb0(x1)) @256^2 ----------------
__global__ void __launch_bounds__(256) img0_kernel(
    const float* __restrict__ rgbf, const unsigned short* __restrict__ x1,
    const float* __restrict__ mt0g, const float* __restrict__ tb,
    float* __restrict__ img0)
{
  __shared__ float mt[768];
  const int tid = threadIdx.x;
  for (int i = tid; i < 768; i += 256) mt[i] = mt0g[i];
  __syncthreads();
  const int p = blockIdx.x * 256 + tid;
  const unsigned short* xp = x1 + (size_t)p * 256;
  float a0 = 0.f, a1 = 0.f, a2 = 0.f;
  for (int i8 = 0; i8 < 32; ++i8) {
    const short8 v = *reinterpret_cast<const short8*>(xp + i8 * 8);
#pragma unroll
    for (int j = 0; j < 8; ++j) {
      const float xv = b2f(v[j]);
      const int ci = i8 * 8 + j;
      a0 = fmaf(mt[ci],       xv, a0);
      a1 = fmaf(mt[256 + ci], xv, a1);
      a2 = fmaf(mt[512 + ci], xv, a2);
    }
  }
  const int oy = p >> 8, ox = p & 255;
  float av[3] = {a0, a1, a2};
#pragma unroll
  for (int o = 0; o < 3; ++o) {
    float y = fminf(fmaxf(av[o] + tb[o], -256.f), 256.f);
    img0[o * 65536 + p] = up2x_sample(rgbf + o * 16384, 128, 128, oy, ox) + y;
  }
}

// ---------------- out = up2x(img0) + clip(sum rgbp + tb) @512^2 ----------------
__global__ void __launch_bounds__(256) final_kernel(
    const float* __restrict__ img0, const float* __restrict__ rgbp,
    const float* __restrict__ tb, float* __restrict__ out)
{
  const int p = blockIdx.x * 256 + threadIdx.x;
  const int oy = p >> 9, ox = p & 511;
#pragma unroll
  for (int o = 0; o < 3; ++o) {
    float a = rgbp[(0 * 3 + o) * 262144 + p] + rgbp[(1 * 3 + o) * 262144 + p];
    float y = fminf(fmaxf(a + tb[o], -256.f), 256.f);
    out[o * 262144 + p] = up2x_sample(img0 + o * 65536, 256, 256, oy, ox) + y;
  }
}

// ---------------- launch ----------------
extern "C" void kernel_launch(void* const* d_in, const int* in_sizes, int n_in,
                              void* d_out, int out_size, void* d_ws, size_t ws_size,
                              hipStream_t stream)
{
  const float* rays   = (const float*)d_in[0];
  const float* rgbs   = (const float*)d_in[1];
  const float* conv_w = (const float*)d_in[2];
  const float* conv_b = (const float*)d_in[3];
  const float* bn_g   = (const float*)d_in[4];
  const float* bn_b   = (const float*)d_in[5];
  const float* bn_m   = (const float*)d_in[6];
  const float* bn_v   = (const float*)d_in[7];
  const float* a0_w   = (const float*)d_in[8];
  const float* a0_b   = (const float*)d_in[9];
  const float* w0     = (const float*)d_in[10];
  const float* b0     = (const float*)d_in[11];
  const float* a1_w   = (const float*)d_in[12];
  const float* a1_b   = (const float*)d_in[13];
  const float* w1     = (const float*)d_in[14];
  const float* b1     = (const float*)d_in[15];
  const float* t0_aw  = (const float*)d_in[16];
  const float* t0_ab  = (const float*)d_in[17];
  const float* t0_w   = (const float*)d_in[18];
  const float* t0_b   = (const float*)d_in[19];
  const float* a2_w   = (const float*)d_in[20];
  const float* a2_b   = (const float*)d_in[21];
  const float* w2     = (const float*)d_in[22];
  const float* b2     = (const float*)d_in[23];
  const float* a3_w   = (const float*)d_in[24];
  const float* a3_b   = (const float*)d_in[25];
  const float* w3     = (const float*)d_in[26];
  const float* b3     = (const float*)d_in[27];
  const float* t1_aw  = (const float*)d_in[28];
  const float* t1_ab  = (const float*)d_in[29];
  const float* t1_w   = (const float*)d_in[30];
  const float* t1_b   = (const float*)d_in[31];

  float* ws  = (float*)d_ws;
  float* out = (float*)d_out;

  unsigned short* wq0   = (unsigned short*)(ws + OFF_WQ0);
  unsigned short* wq1   = (unsigned short*)(ws + OFF_WQ1);
  unsigned short* wq2   = (unsigned short*)(ws + OFF_WQ2);
  unsigned short* wq3   = (unsigned short*)(ws + OFF_WQ3);
  unsigned short* featb = (unsigned short*)(ws + OFF_FEAT);
  unsigned short* ufeat = (unsigned short*)(ws + OFF_UFEAT);
  unsigned short* x0b   = (unsigned short*)(ws + OFF_X0);
  unsigned short* x1b   = (unsigned short*)(ws + OFF_X1);
  unsigned short* x2b   = (unsigned short*)(ws + OFF_X2);
  unsigned short* Ub    = (unsigned short*)(ws + OFF_U);
  const unsigned short* zpage = (const unsigned short*)(ws + OFF_ZERO);

  prep_kernel<<<1, 256, 0, stream>>>(rays, a0_w, a0_b, a1_w, a1_b, t0_aw, t0_ab,
                                     a2_w, a2_b, a3_w, a3_b, t1_aw, t1_ab,
                                     t0_w, t1_w, ws);
  modw_kernel<<<256, 256, 0, stream>>>(w0, ws + OFF_S0, wq0, 32, 256);
  modw_kernel<<<256, 256, 0, stream>>>(w1, ws + OFF_S1, wq1, 256, 256);
  modw_kernel<<<128, 256, 0, stream>>>(w2, ws + OFF_S2, wq2, 256, 128);
  modw_kernel<<<128, 256, 0, stream>>>(w3, ws + OFF_S3, wq3, 128, 128);
  feat_kernel<<<64, 256, 0, stream>>>(rgbs, conv_w, conv_b, bn_g, bn_b, bn_m, bn_v,
                                      featb, ws + OFF_RGBF);
  // up(feat) -> ufeat  (128->256, C=32: c8s=2, w2s=8)
  up2x_nhwc_kernel<<<1024, 256, 0, stream>>>(featb, ufeat, 128, 128, 2, 8);
  // L0: ufeat(32) -> x0(256) @256^2
  conv3x3_mfma<false><<<dim3(128, 2), 512, 0, stream>>>(
      ufeat, wq0, b0, x0b, nullptr, nullptr, zpage, 256, 256, 32, 256);
  // L1: x0(256) -> x1(256) @256^2
  conv3x3_mfma<false><<<dim3(128, 2), 512, 0, stream>>>(
      x0b, wq1, b1, x1b, nullptr, nullptr, zpage, 256, 256, 256, 256);
  // img0 = up2x(rgb) + to_rgb0(x1)
  img0_kernel<<<256, 256, 0, stream>>>(ws + OFF_RGBF, x1b, ws + OFF_MT0, t0_b,
                                       ws + OFF_IMG0);
  // up(x1) -> U  (256->512, C=256: c8s=5, w2s=9)
  up2x_nhwc_kernel<<<32768, 256, 0, stream>>>(x1b, Ub, 256, 256, 5, 9);
  // L2: U(256) -> x2(128) @512^2
  conv3x3_mfma<false><<<dim3(512, 1), 512, 0, stream>>>(
      Ub, wq2, b2, x2b, nullptr, nullptr, zpage, 512, 512, 256, 128);
  // L3: x2(128) -> fused to_rgb1 partials @512^2
  conv3x3_mfma<true><<<dim3(512, 1), 512, 0, stream>>>(
      x2b, wq3, b3, nullptr, ws + OFF_MT1, ws + OFF_RGBP, zpage, 512, 512, 128, 128);
  // out = up2x(img0) + clip(rgbp sum + t1_b)
  final_kernel<<<1024, 256, 0, stream>>>(ws + OFF_IMG0, ws + OFF_RGBP, t1_b, out);
}